// Round 1
// baseline (410.440 us; speedup 1.0000x reference)
//
#include <hip/hip_runtime.h>

// dims
#define L_DIM 1024
#define E_DIM 1024
#define NB 4
#define H_NUM 16
#define HD_DIM 64
#define T_TOK 4096   // L*NB
#define NHB 64       // NB*H_NUM

typedef float f32x4 __attribute__((ext_vector_type(4)));
typedef unsigned short u16x8 __attribute__((ext_vector_type(8)));
typedef unsigned short u16x4 __attribute__((ext_vector_type(4)));
typedef __bf16 bf16x8 __attribute__((ext_vector_type(8)));

__device__ inline unsigned short f2bf(float f) {
  unsigned int u = __builtin_bit_cast(unsigned int, f);
  u += 0x7FFFu + ((u >> 16) & 1u);
  return (unsigned short)(u >> 16);
}
__device__ inline float bf2f(unsigned short h) {
  unsigned int u = ((unsigned int)h) << 16;
  return __builtin_bit_cast(float, u);
}
__device__ inline f32x4 mfma16(u16x8 a, u16x8 b, f32x4 c) {
  return __builtin_amdgcn_mfma_f32_16x16x32_bf16(
      __builtin_bit_cast(bf16x8, a), __builtin_bit_cast(bf16x8, b), c, 0, 0, 0);
}

// ---------------- K1: packed QKV projection ----------------
// X (T x E) @ Wc^T (E x E) + bias -> bf16, head-major layouts.
// grid: (32 m-tiles, 8 n-tiles, 3 chunks), block 256
__global__ __launch_bounds__(256) void qkv_proj_kernel(
    const float* __restrict__ qin, const float* __restrict__ kin,
    const float* __restrict__ vin, const float* __restrict__ W,
    const float* __restrict__ bias, unsigned short* __restrict__ q_hm,
    unsigned short* __restrict__ k_hm, unsigned short* __restrict__ v_t) {
  __shared__ __align__(16) unsigned short As[128][40];
  __shared__ __align__(16) unsigned short Bs[128][40];
  const int tid = threadIdx.x;
  const int bm = blockIdx.x;
  const int bn = blockIdx.y;
  const int z = blockIdx.z;
  const float* X = (z == 0) ? qin : (z == 1) ? kin : vin;
  const float* Wc = W + (size_t)z * E_DIM * E_DIM;
  const float* bc = bias + z * E_DIM;

  const int w = tid >> 6, lane = tid & 63;
  const int wm = w & 1, wn = w >> 1;
  const int quad = lane >> 4, l16 = lane & 15;

  f32x4 acc[4][4];
  for (int i = 0; i < 4; i++)
    for (int j = 0; j < 4; j++) { f32x4 zz = {0.f, 0.f, 0.f, 0.f}; acc[i][j] = zz; }

  const int r0 = tid >> 3;        // 0..31
  const int kc = (tid & 7) * 4;   // 0..28

  for (int k0 = 0; k0 < E_DIM; k0 += 32) {
    for (int rr = 0; rr < 4; rr++) {
      int row = r0 + rr * 32;
      float4 va = *(const float4*)&X[(size_t)(bm * 128 + row) * E_DIM + k0 + kc];
      u16x4 ha = {f2bf(va.x), f2bf(va.y), f2bf(va.z), f2bf(va.w)};
      *(u16x4*)&As[row][kc] = ha;
      float4 vb = *(const float4*)&Wc[(size_t)(bn * 128 + row) * E_DIM + k0 + kc];
      u16x4 hb = {f2bf(vb.x), f2bf(vb.y), f2bf(vb.z), f2bf(vb.w)};
      *(u16x4*)&Bs[row][kc] = hb;
    }
    __syncthreads();
    u16x8 af[4], bfv[4];
    for (int mi = 0; mi < 4; mi++)
      af[mi] = *(const u16x8*)&As[wm * 64 + mi * 16 + l16][quad * 8];
    for (int ni = 0; ni < 4; ni++)
      bfv[ni] = *(const u16x8*)&Bs[wn * 64 + ni * 16 + l16][quad * 8];
    for (int mi = 0; mi < 4; mi++)
      for (int ni = 0; ni < 4; ni++)
        acc[mi][ni] = mfma16(af[mi], bfv[ni], acc[mi][ni]);
    __syncthreads();
  }
  for (int ni = 0; ni < 4; ni++) {
    int col = bn * 128 + wn * 64 + ni * 16 + l16;
    float bv = bc[col];
    int h = col >> 6, d = col & 63;
    for (int mi = 0; mi < 4; mi++) {
      for (int r = 0; r < 4; r++) {
        int t = bm * 128 + wm * 64 + mi * 16 + quad * 4 + r;
        float v = acc[mi][ni][r] + bv;
        int nb = t & 3, pos = t >> 2;
        if (z == 0) {
          v *= 0.125f;  // scaling = HD^-0.5
          q_hm[(size_t)((nb * 16 + h) * 1024 + pos) * 64 + d] = f2bf(v);
        } else if (z == 1) {
          k_hm[(size_t)((nb * 16 + h) * 1024 + pos) * 64 + d] = f2bf(v);
        } else {
          v_t[(size_t)((nb * 16 + h) * 64 + d) * 1024 + pos] = f2bf(v);
        }
      }
    }
  }
}

// ---------------- K3: attention core (scores -> softmax -> PV) ----------------
// block = (l-tile of 16, head b). grid (64, 64), block 256 (4 waves).
__global__ __launch_bounds__(256) void attn_kernel(
    const unsigned short* __restrict__ q_hm, const unsigned short* __restrict__ k_hm,
    const unsigned short* __restrict__ v_t, unsigned short* __restrict__ o_h,
    float* __restrict__ m_ws, float* __restrict__ r_ws) {
  __shared__ __align__(16) unsigned short sc[16][1032];
  __shared__ float red[16][16];
  __shared__ float mrow[16];
  __shared__ float rrow[16];
  const int tid = threadIdx.x;
  const int l0 = blockIdx.x * 16;
  const int b = blockIdx.y;
  const int nb = b >> 4, h = b & 15;
  const int w = tid >> 6, lane = tid & 63;
  const int quad = lane >> 4, l16 = lane & 15;

  // phase 1: scores[16][s], wave w covers s in [w*256, w*256+256)
  u16x8 aq0, aq1;
  {
    const unsigned short* qp = &q_hm[(size_t)(b * 1024 + l0 + l16) * 64 + quad * 8];
    aq0 = *(const u16x8*)qp;
    aq1 = *(const u16x8*)(qp + 32);
  }
  for (int st = 0; st < 16; st++) {
    int s0 = w * 256 + st * 16;
    const unsigned short* kp = &k_hm[(size_t)(b * 1024 + s0 + l16) * 64 + quad * 8];
    u16x8 bk0 = *(const u16x8*)kp;
    u16x8 bk1 = *(const u16x8*)(kp + 32);
    f32x4 a = {0.f, 0.f, 0.f, 0.f};
    a = mfma16(aq0, bk0, a);
    a = mfma16(aq1, bk1, a);
    for (int r = 0; r < 4; r++)
      sc[quad * 4 + r][s0 + l16] = f2bf(a[r]);
  }
  __syncthreads();

  // phase 2: row max + expsum; exp in place
  const int rI = tid >> 4;
  const int sI = tid & 15;
  float lmax = -1e30f;
  for (int s = sI; s < 1024; s += 16) lmax = fmaxf(lmax, bf2f(sc[rI][s]));
  red[rI][sI] = lmax;
  __syncthreads();
  if (tid < 16) {
    float m = red[tid][0];
    for (int i = 1; i < 16; i++) m = fmaxf(m, red[tid][i]);
    mrow[tid] = m;
  }
  __syncthreads();
  float mv = mrow[rI];
  float lsum = 0.f;
  for (int s = sI; s < 1024; s += 16) {
    float e = __expf(bf2f(sc[rI][s]) - mv);
    lsum += e;
    sc[rI][s] = f2bf(e);
  }
  red[rI][sI] = lsum;
  __syncthreads();
  if (tid < 16) {
    float sm = 0.f;
    for (int i = 0; i < 16; i++) sm += red[tid][i];
    float rv = 1.0f / sm;
    rrow[tid] = rv;
    m_ws[b * 1024 + l0 + tid] = mrow[tid];
    r_ws[b * 1024 + l0 + tid] = rv;
  }
  __syncthreads();

  // phase 3: PV. wave w handles d-tile [w*16, w*16+16)
  f32x4 acc = {0.f, 0.f, 0.f, 0.f};
  const unsigned short* vp = &v_t[(size_t)(b * 64 + w * 16 + l16) * 1024];
  for (int s0 = 0; s0 < 1024; s0 += 32) {
    u16x8 ae = *(const u16x8*)&sc[l16][s0 + quad * 8];
    u16x8 bv = *(const u16x8*)(vp + s0 + quad * 8);
    acc = mfma16(ae, bv, acc);
  }
  for (int r = 0; r < 4; r++) {
    int lr = quad * 4 + r;
    float val = acc[r] * rrow[lr];
    int t = (l0 + lr) * 4 + nb;
    o_h[(size_t)t * E_DIM + h * 64 + w * 16 + l16] = f2bf(val);
  }
}

// ---------------- K4: head-averaged attn + sigmoid weights ----------------
// block covers (n, 64 L-rows, 64 S-cols); loops 16 heads, acc in registers.
// grid (16 s-tiles, 16 l-tiles, 4 n), block 256.
__global__ __launch_bounds__(256) void weights_kernel(
    const unsigned short* __restrict__ q_hm, const unsigned short* __restrict__ k_hm,
    const float* __restrict__ m_ws, const float* __restrict__ r_ws,
    float* __restrict__ attn_out, float* __restrict__ sig_out) {
  const int tid = threadIdx.x;
  const int s0 = blockIdx.x * 64;
  const int l0 = blockIdx.y * 64;
  const int nb = blockIdx.z;
  const int w = tid >> 6, lane = tid & 63;
  const int quad = lane >> 4, l16 = lane & 15;
  const int lrow0 = l0 + w * 16;

  f32x4 accA[4], accS[4];
  for (int i = 0; i < 4; i++) {
    f32x4 zz = {0.f, 0.f, 0.f, 0.f};
    accA[i] = zz; accS[i] = zz;
  }

  for (int h = 0; h < 16; h++) {
    int b = nb * 16 + h;
    const unsigned short* qp = &q_hm[(size_t)(b * 1024 + lrow0 + l16) * 64 + quad * 8];
    u16x8 a0 = *(const u16x8*)qp;
    u16x8 a1 = *(const u16x8*)(qp + 32);
    float mv[4], rv[4];
    for (int r = 0; r < 4; r++) {
      int l = lrow0 + quad * 4 + r;
      mv[r] = m_ws[b * 1024 + l];
      rv[r] = r_ws[b * 1024 + l];
    }
    for (int ni = 0; ni < 4; ni++) {
      int st = s0 + ni * 16;
      const unsigned short* kp = &k_hm[(size_t)(b * 1024 + st + l16) * 64 + quad * 8];
      u16x8 b0 = *(const u16x8*)kp;
      u16x8 b1 = *(const u16x8*)(kp + 32);
      f32x4 scv = {0.f, 0.f, 0.f, 0.f};
      scv = mfma16(a0, b0, scv);
      scv = mfma16(a1, b1, scv);
      for (int r = 0; r < 4; r++) {
        float s = scv[r];
        accA[ni][r] += __expf(s - mv[r]) * rv[r];
        accS[ni][r] += __builtin_amdgcn_rcpf(1.0f + __expf(-s));
      }
    }
  }
  const float inv_h = 1.0f / 16.0f;
  for (int ni = 0; ni < 4; ni++) {
    for (int r = 0; r < 4; r++) {
      int l = lrow0 + quad * 4 + r;
      int s = s0 + ni * 16 + l16;
      size_t idx = ((size_t)nb * 1024 + l) * 1024 + s;
      attn_out[idx] = accA[ni][r] * inv_h;
      sig_out[idx] = accS[ni][r] * inv_h;
    }
  }
}

// ---------------- K5: output projection ----------------
// o_h (T x E bf16) @ Wout^T + bias -> out f32 (t,e). grid (32,8), block 256.
__global__ __launch_bounds__(256) void out_proj_kernel(
    const unsigned short* __restrict__ o_h, const float* __restrict__ W,
    const float* __restrict__ bias, float* __restrict__ out) {
  __shared__ __align__(16) unsigned short As[128][40];
  __shared__ __align__(16) unsigned short Bs[128][40];
  const int tid = threadIdx.x;
  const int bm = blockIdx.x, bn = blockIdx.y;
  const int w = tid >> 6, lane = tid & 63;
  const int wm = w & 1, wn = w >> 1;
  const int quad = lane >> 4, l16 = lane & 15;
  f32x4 acc[4][4];
  for (int i = 0; i < 4; i++)
    for (int j = 0; j < 4; j++) { f32x4 zz = {0.f, 0.f, 0.f, 0.f}; acc[i][j] = zz; }

  const int r0 = tid >> 3, kc = (tid & 7) * 4;
  const int ra = tid >> 2, ca = (tid & 3) * 8;

  for (int k0 = 0; k0 < E_DIM; k0 += 32) {
    for (int rr = 0; rr < 2; rr++) {
      int row = ra + rr * 64;
      u16x8 va = *(const u16x8*)&o_h[(size_t)(bm * 128 + row) * E_DIM + k0 + ca];
      *(u16x8*)&As[row][ca] = va;
    }
    for (int rr = 0; rr < 4; rr++) {
      int row = r0 + rr * 32;
      float4 vb = *(const float4*)&W[(size_t)(bn * 128 + row) * E_DIM + k0 + kc];
      u16x4 hb = {f2bf(vb.x), f2bf(vb.y), f2bf(vb.z), f2bf(vb.w)};
      *(u16x4*)&Bs[row][kc] = hb;
    }
    __syncthreads();
    u16x8 af[4], bfv[4];
    for (int mi = 0; mi < 4; mi++)
      af[mi] = *(const u16x8*)&As[wm * 64 + mi * 16 + l16][quad * 8];
    for (int ni = 0; ni < 4; ni++)
      bfv[ni] = *(const u16x8*)&Bs[wn * 64 + ni * 16 + l16][quad * 8];
    for (int mi = 0; mi < 4; mi++)
      for (int ni = 0; ni < 4; ni++)
        acc[mi][ni] = mfma16(af[mi], bfv[ni], acc[mi][ni]);
    __syncthreads();
  }
  for (int ni = 0; ni < 4; ni++) {
    int col = bn * 128 + wn * 64 + ni * 16 + l16;
    float bv = bias[col];
    for (int mi = 0; mi < 4; mi++) {
      for (int r = 0; r < 4; r++) {
        int t = bm * 128 + wm * 64 + mi * 16 + quad * 4 + r;
        out[(size_t)t * E_DIM + col] = acc[mi][ni][r] + bv;
      }
    }
  }
}

extern "C" void kernel_launch(void* const* d_in, const int* in_sizes, int n_in,
                              void* d_out, int out_size, void* d_ws, size_t ws_size,
                              hipStream_t stream) {
  const float* qin  = (const float*)d_in[0];
  const float* kin  = (const float*)d_in[1];
  const float* vin  = (const float*)d_in[2];
  const float* Wqkv = (const float*)d_in[3];
  const float* bqkv = (const float*)d_in[4];
  const float* Wout = (const float*)d_in[5];
  const float* bout = (const float*)d_in[6];
  float* out      = (float*)d_out;
  float* attn_out = out + 4194304;   // (N,L,S)
  float* sig_out  = out + 8388608;   // (N,L,S)

  unsigned short* q_hm = (unsigned short*)d_ws;      // [64][1024][64] bf16
  unsigned short* k_hm = q_hm + 4194304;             // [64][1024][64]
  unsigned short* v_t  = q_hm + 8388608;             // [64][64][1024]
  unsigned short* o_h  = q_hm + 12582912;            // [4096][1024]
  float* m_ws = (float*)(q_hm + 16777216);           // [64*1024]
  float* r_ws = m_ws + 65536;                        // [64*1024]

  qkv_proj_kernel<<<dim3(32, 8, 3), 256, 0, stream>>>(qin, kin, vin, Wqkv, bqkv,
                                                      q_hm, k_hm, v_t);
  attn_kernel<<<dim3(64, 64), 256, 0, stream>>>(q_hm, k_hm, v_t, o_h, m_ws, r_ws);
  weights_kernel<<<dim3(16, 16, 4), 256, 0, stream>>>(q_hm, k_hm, m_ws, r_ws,
                                                      attn_out, sig_out);
  out_proj_kernel<<<dim3(32, 8), 256, 0, stream>>>(o_h, Wout, bout, out);
}

// Round 2
// 409.331 us; speedup vs baseline: 1.0027x; 1.0027x over previous
//
#include <hip/hip_runtime.h>

// dims
#define L_DIM 1024
#define E_DIM 1024
#define NB 4
#define H_NUM 16
#define HD_DIM 64
#define T_TOK 4096   // L*NB
#define NHB 64       // NB*H_NUM

typedef float f32x4 __attribute__((ext_vector_type(4)));
typedef unsigned short u16x8 __attribute__((ext_vector_type(8)));
typedef unsigned short u16x4 __attribute__((ext_vector_type(4)));
typedef __bf16 bf16x8 __attribute__((ext_vector_type(8)));

__device__ inline unsigned short f2bf(float f) {
  unsigned int u = __builtin_bit_cast(unsigned int, f);
  u += 0x7FFFu + ((u >> 16) & 1u);
  return (unsigned short)(u >> 16);
}
__device__ inline float bf2f(unsigned short h) {
  unsigned int u = ((unsigned int)h) << 16;
  return __builtin_bit_cast(float, u);
}
__device__ inline f32x4 mfma16(u16x8 a, u16x8 b, f32x4 c) {
  return __builtin_amdgcn_mfma_f32_16x16x32_bf16(
      __builtin_bit_cast(bf16x8, a), __builtin_bit_cast(bf16x8, b), c, 0, 0, 0);
}

// ---------------- K1: packed QKV projection ----------------
// X (T x E) @ Wc^T (E x E) + bias -> bf16, head-major layouts.
// grid: (32 m-tiles, 8 n-tiles, 3 chunks), block 256
__global__ __launch_bounds__(256) void qkv_proj_kernel(
    const float* __restrict__ qin, const float* __restrict__ kin,
    const float* __restrict__ vin, const float* __restrict__ W,
    const float* __restrict__ bias, unsigned short* __restrict__ q_hm,
    unsigned short* __restrict__ k_hm, unsigned short* __restrict__ v_t) {
  __shared__ __align__(16) unsigned short As[128][40];
  __shared__ __align__(16) unsigned short Bs[128][40];
  const int tid = threadIdx.x;
  const int bm = blockIdx.x;
  const int bn = blockIdx.y;
  const int z = blockIdx.z;
  const float* X = (z == 0) ? qin : (z == 1) ? kin : vin;
  const float* Wc = W + (size_t)z * E_DIM * E_DIM;
  const float* bc = bias + z * E_DIM;

  const int w = tid >> 6, lane = tid & 63;
  const int wm = w & 1, wn = w >> 1;
  const int quad = lane >> 4, l16 = lane & 15;

  f32x4 acc[4][4];
  for (int i = 0; i < 4; i++)
    for (int j = 0; j < 4; j++) { f32x4 zz = {0.f, 0.f, 0.f, 0.f}; acc[i][j] = zz; }

  const int r0 = tid >> 3;        // 0..31
  const int kc = (tid & 7) * 4;   // 0..28

  for (int k0 = 0; k0 < E_DIM; k0 += 32) {
    for (int rr = 0; rr < 4; rr++) {
      int row = r0 + rr * 32;
      float4 va = *(const float4*)&X[(size_t)(bm * 128 + row) * E_DIM + k0 + kc];
      u16x4 ha = {f2bf(va.x), f2bf(va.y), f2bf(va.z), f2bf(va.w)};
      *(u16x4*)&As[row][kc] = ha;
      float4 vb = *(const float4*)&Wc[(size_t)(bn * 128 + row) * E_DIM + k0 + kc];
      u16x4 hb = {f2bf(vb.x), f2bf(vb.y), f2bf(vb.z), f2bf(vb.w)};
      *(u16x4*)&Bs[row][kc] = hb;
    }
    __syncthreads();
    u16x8 af[4], bfv[4];
    for (int mi = 0; mi < 4; mi++)
      af[mi] = *(const u16x8*)&As[wm * 64 + mi * 16 + l16][quad * 8];
    for (int ni = 0; ni < 4; ni++)
      bfv[ni] = *(const u16x8*)&Bs[wn * 64 + ni * 16 + l16][quad * 8];
    for (int mi = 0; mi < 4; mi++)
      for (int ni = 0; ni < 4; ni++)
        acc[mi][ni] = mfma16(af[mi], bfv[ni], acc[mi][ni]);
    __syncthreads();
  }
  for (int ni = 0; ni < 4; ni++) {
    int col = bn * 128 + wn * 64 + ni * 16 + l16;
    float bv = bc[col];
    int h = col >> 6, d = col & 63;
    for (int mi = 0; mi < 4; mi++) {
      for (int r = 0; r < 4; r++) {
        int t = bm * 128 + wm * 64 + mi * 16 + quad * 4 + r;
        float v = acc[mi][ni][r] + bv;
        int nb = t & 3, pos = t >> 2;
        if (z == 0) {
          v *= 0.125f;  // scaling = HD^-0.5
          q_hm[(size_t)((nb * 16 + h) * 1024 + pos) * 64 + d] = f2bf(v);
        } else if (z == 1) {
          k_hm[(size_t)((nb * 16 + h) * 1024 + pos) * 64 + d] = f2bf(v);
        } else {
          v_t[(size_t)((nb * 16 + h) * 64 + d) * 1024 + pos] = f2bf(v);
        }
      }
    }
  }
}

// ---------------- K3: attention core (scores -> softmax -> PV) ----------------
// block = (32 L rows, head b). 512 threads = 8 waves. grid (32, 64).
// Wave w: half = w>>2 picks 16 L rows; sq = w&3 picks 256-wide S quarter.
// Scores computed with A=K, B=Q so D[s][l]: each lane's 64 score values all
// belong to ONE l-row (l = l16) -> softmax stats in registers + 2 shfl_xor.
__global__ __launch_bounds__(512, 4) void attn_kernel(
    const unsigned short* __restrict__ q_hm, const unsigned short* __restrict__ k_hm,
    const unsigned short* __restrict__ v_t, unsigned short* __restrict__ o_h,
    float* __restrict__ m_ws, float* __restrict__ r_ws) {
  __shared__ __align__(16) unsigned short sc[32][1032];  // P (exp'd scores) bf16
  __shared__ float red_m[8][16];
  __shared__ float red_s[8][16];
  const int tid = threadIdx.x;
  const int l0 = blockIdx.x * 32;
  const int b = blockIdx.y;
  const int nb = b >> 4, h = b & 15;
  const int w = tid >> 6, lane = tid & 63;
  const int quad = lane >> 4, l16 = lane & 15;
  const int half = w >> 2;   // which 16-row group
  const int sq = w & 3;      // which 256-wide s quarter
  const int rowbase = half * 16;

  // ---- phase 1: scores for (16 l-rows) x (256 s) in registers ----
  u16x8 bq0, bq1;
  {
    const unsigned short* qp = &q_hm[(size_t)(b * 1024 + l0 + rowbase + l16) * 64 + quad * 8];
    bq0 = *(const u16x8*)qp;
    bq1 = *(const u16x8*)(qp + 32);
  }
  f32x4 acc[16];
  for (int st = 0; st < 16; st++) { f32x4 zz = {0.f, 0.f, 0.f, 0.f}; acc[st] = zz; }
  for (int st = 0; st < 16; st++) {
    int sbase = sq * 256 + st * 16;
    const unsigned short* kp = &k_hm[(size_t)(b * 1024 + sbase + l16) * 64 + quad * 8];
    u16x8 ak0 = *(const u16x8*)kp;
    u16x8 ak1 = *(const u16x8*)(kp + 32);
    acc[st] = mfma16(ak0, bq0, acc[st]);
    acc[st] = mfma16(ak1, bq1, acc[st]);
  }

  // ---- phase 2: softmax stats in registers ----
  float lm = -1e30f;
  for (int st = 0; st < 16; st++)
    for (int r = 0; r < 4; r++) lm = fmaxf(lm, acc[st][r]);
  lm = fmaxf(lm, __shfl_xor(lm, 16, 64));
  lm = fmaxf(lm, __shfl_xor(lm, 32, 64));
  if (lane < 16) red_m[w][lane] = lm;
  __syncthreads();
  float m4 = red_m[half * 4 + 0][l16];
  m4 = fmaxf(m4, red_m[half * 4 + 1][l16]);
  m4 = fmaxf(m4, red_m[half * 4 + 2][l16]);
  m4 = fmaxf(m4, red_m[half * 4 + 3][l16]);

  float ls = 0.f;
  for (int st = 0; st < 16; st++) {
    f32x4 e;
    for (int r = 0; r < 4; r++) e[r] = __expf(acc[st][r] - m4);
    ls += e[0] + e[1] + e[2] + e[3];
    u16x4 p = {f2bf(e[0]), f2bf(e[1]), f2bf(e[2]), f2bf(e[3])};
    // lane holds s = sq*256 + st*16 + quad*4 + r for l = rowbase + l16
    *(u16x4*)&sc[rowbase + l16][sq * 256 + st * 16 + quad * 4] = p;
  }
  ls += __shfl_xor(ls, 16, 64);
  ls += __shfl_xor(ls, 32, 64);
  if (lane < 16) red_s[w][lane] = ls;
  __syncthreads();
  float s4 = red_s[half * 4 + 0][l16] + red_s[half * 4 + 1][l16] +
             red_s[half * 4 + 2][l16] + red_s[half * 4 + 3][l16];
  float rv = 1.0f / s4;  // every lane: 1/rowsum for row (l0 + rowbase + l16)
  if (sq == 0 && lane < 16) {
    m_ws[b * 1024 + l0 + rowbase + lane] = m4;
    r_ws[b * 1024 + l0 + rowbase + lane] = rv;
  }

  // ---- phase 3: PV. wave w: l-half = w>>2, d-tile = (w&3)*16 ----
  const int halfp = w >> 2;
  const int dtile = (w & 3) * 16;
  f32x4 oacc = {0.f, 0.f, 0.f, 0.f};
  const unsigned short* vp = &v_t[(size_t)(b * 64 + dtile + l16) * 1024];
  for (int s0 = 0; s0 < 1024; s0 += 32) {
    u16x8 ae = *(const u16x8*)&sc[halfp * 16 + l16][s0 + quad * 8];
    u16x8 bv = *(const u16x8*)(vp + s0 + quad * 8);
    oacc = mfma16(ae, bv, oacc);
  }
  for (int r = 0; r < 4; r++) {
    int lr = quad * 4 + r;                        // local row within half
    float rv_r = __shfl(rv, lr, 64);              // rv lives in lane l16==lr
    float val = oacc[r] * rv_r;
    int t = (l0 + halfp * 16 + lr) * 4 + nb;
    o_h[(size_t)t * E_DIM + h * 64 + dtile + l16] = f2bf(val);
  }
}

// ---------------- K4: head-averaged attn + sigmoid weights ----------------
// block covers (n, 64 L-rows, 64 S-cols); loops 16 heads, acc in registers.
// grid (16 s-tiles, 16 l-tiles, 4 n), block 256.
__global__ __launch_bounds__(256) void weights_kernel(
    const unsigned short* __restrict__ q_hm, const unsigned short* __restrict__ k_hm,
    const float* __restrict__ m_ws, const float* __restrict__ r_ws,
    float* __restrict__ attn_out, float* __restrict__ sig_out) {
  const int tid = threadIdx.x;
  const int s0 = blockIdx.x * 64;
  const int l0 = blockIdx.y * 64;
  const int nb = blockIdx.z;
  const int w = tid >> 6, lane = tid & 63;
  const int quad = lane >> 4, l16 = lane & 15;
  const int lrow0 = l0 + w * 16;

  f32x4 accA[4], accS[4];
  for (int i = 0; i < 4; i++) {
    f32x4 zz = {0.f, 0.f, 0.f, 0.f};
    accA[i] = zz; accS[i] = zz;
  }

  for (int h = 0; h < 16; h++) {
    int b = nb * 16 + h;
    const unsigned short* qp = &q_hm[(size_t)(b * 1024 + lrow0 + l16) * 64 + quad * 8];
    u16x8 a0 = *(const u16x8*)qp;
    u16x8 a1 = *(const u16x8*)(qp + 32);
    float mv[4], rv[4];
    for (int r = 0; r < 4; r++) {
      int l = lrow0 + quad * 4 + r;
      mv[r] = m_ws[b * 1024 + l];
      rv[r] = r_ws[b * 1024 + l];
    }
    for (int ni = 0; ni < 4; ni++) {
      int st = s0 + ni * 16;
      const unsigned short* kp = &k_hm[(size_t)(b * 1024 + st + l16) * 64 + quad * 8];
      u16x8 b0 = *(const u16x8*)kp;
      u16x8 b1 = *(const u16x8*)(kp + 32);
      f32x4 scv = {0.f, 0.f, 0.f, 0.f};
      scv = mfma16(a0, b0, scv);
      scv = mfma16(a1, b1, scv);
      for (int r = 0; r < 4; r++) {
        float s = scv[r];
        accA[ni][r] += __expf(s - mv[r]) * rv[r];
        accS[ni][r] += __builtin_amdgcn_rcpf(1.0f + __expf(-s));
      }
    }
  }
  const float inv_h = 1.0f / 16.0f;
  for (int ni = 0; ni < 4; ni++) {
    for (int r = 0; r < 4; r++) {
      int l = lrow0 + quad * 4 + r;
      int s = s0 + ni * 16 + l16;
      size_t idx = ((size_t)nb * 1024 + l) * 1024 + s;
      attn_out[idx] = accA[ni][r] * inv_h;
      sig_out[idx] = accS[ni][r] * inv_h;
    }
  }
}

// ---------------- K5: output projection ----------------
// o_h (T x E bf16) @ Wout^T + bias -> out f32 (t,e). grid (32,8), block 256.
__global__ __launch_bounds__(256) void out_proj_kernel(
    const unsigned short* __restrict__ o_h, const float* __restrict__ W,
    const float* __restrict__ bias, float* __restrict__ out) {
  __shared__ __align__(16) unsigned short As[128][40];
  __shared__ __align__(16) unsigned short Bs[128][40];
  const int tid = threadIdx.x;
  const int bm = blockIdx.x, bn = blockIdx.y;
  const int w = tid >> 6, lane = tid & 63;
  const int wm = w & 1, wn = w >> 1;
  const int quad = lane >> 4, l16 = lane & 15;
  f32x4 acc[4][4];
  for (int i = 0; i < 4; i++)
    for (int j = 0; j < 4; j++) { f32x4 zz = {0.f, 0.f, 0.f, 0.f}; acc[i][j] = zz; }

  const int r0 = tid >> 3, kc = (tid & 7) * 4;
  const int ra = tid >> 2, ca = (tid & 3) * 8;

  for (int k0 = 0; k0 < E_DIM; k0 += 32) {
    for (int rr = 0; rr < 2; rr++) {
      int row = ra + rr * 64;
      u16x8 va = *(const u16x8*)&o_h[(size_t)(bm * 128 + row) * E_DIM + k0 + ca];
      *(u16x8*)&As[row][ca] = va;
    }
    for (int rr = 0; rr < 4; rr++) {
      int row = r0 + rr * 32;
      float4 vb = *(const float4*)&W[(size_t)(bn * 128 + row) * E_DIM + k0 + kc];
      u16x4 hb = {f2bf(vb.x), f2bf(vb.y), f2bf(vb.z), f2bf(vb.w)};
      *(u16x4*)&Bs[row][kc] = hb;
    }
    __syncthreads();
    u16x8 af[4], bfv[4];
    for (int mi = 0; mi < 4; mi++)
      af[mi] = *(const u16x8*)&As[wm * 64 + mi * 16 + l16][quad * 8];
    for (int ni = 0; ni < 4; ni++)
      bfv[ni] = *(const u16x8*)&Bs[wn * 64 + ni * 16 + l16][quad * 8];
    for (int mi = 0; mi < 4; mi++)
      for (int ni = 0; ni < 4; ni++)
        acc[mi][ni] = mfma16(af[mi], bfv[ni], acc[mi][ni]);
    __syncthreads();
  }
  for (int ni = 0; ni < 4; ni++) {
    int col = bn * 128 + wn * 64 + ni * 16 + l16;
    float bv = bias[col];
    for (int mi = 0; mi < 4; mi++) {
      for (int r = 0; r < 4; r++) {
        int t = bm * 128 + wm * 64 + mi * 16 + quad * 4 + r;
        out[(size_t)t * E_DIM + col] = acc[mi][ni][r] + bv;
      }
    }
  }
}

extern "C" void kernel_launch(void* const* d_in, const int* in_sizes, int n_in,
                              void* d_out, int out_size, void* d_ws, size_t ws_size,
                              hipStream_t stream) {
  const float* qin  = (const float*)d_in[0];
  const float* kin  = (const float*)d_in[1];
  const float* vin  = (const float*)d_in[2];
  const float* Wqkv = (const float*)d_in[3];
  const float* bqkv = (const float*)d_in[4];
  const float* Wout = (const float*)d_in[5];
  const float* bout = (const float*)d_in[6];
  float* out      = (float*)d_out;
  float* attn_out = out + 4194304;   // (N,L,S)
  float* sig_out  = out + 8388608;   // (N,L,S)

  unsigned short* q_hm = (unsigned short*)d_ws;      // [64][1024][64] bf16
  unsigned short* k_hm = q_hm + 4194304;             // [64][1024][64]
  unsigned short* v_t  = q_hm + 8388608;             // [64][64][1024]
  unsigned short* o_h  = q_hm + 12582912;            // [4096][1024]
  float* m_ws = (float*)(q_hm + 16777216);           // [64*1024]
  float* r_ws = m_ws + 65536;                        // [64*1024]

  qkv_proj_kernel<<<dim3(32, 8, 3), 256, 0, stream>>>(qin, kin, vin, Wqkv, bqkv,
                                                      q_hm, k_hm, v_t);
  attn_kernel<<<dim3(32, 64), 512, 0, stream>>>(q_hm, k_hm, v_t, o_h, m_ws, r_ws);
  weights_kernel<<<dim3(16, 16, 4), 256, 0, stream>>>(q_hm, k_hm, m_ws, r_ws,
                                                      attn_out, sig_out);
  out_proj_kernel<<<dim3(32, 8), 256, 0, stream>>>(o_h, Wout, bout, out);
}

// Round 3
// 368.486 us; speedup vs baseline: 1.1139x; 1.1108x over previous
//
#include <hip/hip_runtime.h>

// dims
#define L_DIM 1024
#define E_DIM 1024
#define NB 4
#define H_NUM 16
#define HD_DIM 64
#define T_TOK 4096   // L*NB
#define NHB 64       // NB*H_NUM

typedef float f32x4 __attribute__((ext_vector_type(4)));
typedef unsigned short u16x8 __attribute__((ext_vector_type(8)));
typedef unsigned short u16x4 __attribute__((ext_vector_type(4)));
typedef __bf16 bf16x8 __attribute__((ext_vector_type(8)));

__device__ inline unsigned short f2bf(float f) {
  unsigned int u = __builtin_bit_cast(unsigned int, f);
  u += 0x7FFFu + ((u >> 16) & 1u);
  return (unsigned short)(u >> 16);
}
__device__ inline f32x4 mfma16(u16x8 a, u16x8 b, f32x4 c) {
  return __builtin_amdgcn_mfma_f32_16x16x32_bf16(
      __builtin_bit_cast(bf16x8, a), __builtin_bit_cast(bf16x8, b), c, 0, 0, 0);
}

// async global->LDS 16B copy (CK-style casts; LDS offset = low 32 bits of flat)
__device__ __forceinline__ void gl2lds16(const void* g, void* l) {
  auto gp = reinterpret_cast<const __attribute__((address_space(1))) unsigned int*>(
      reinterpret_cast<unsigned long long>(g));
  auto lp = reinterpret_cast<__attribute__((address_space(3))) unsigned int*>(
      static_cast<unsigned int>(reinterpret_cast<unsigned long long>(l)));
  __builtin_amdgcn_global_load_lds(gp, lp, 16, 0, 0);
}

// ---------------- K1: packed QKV projection ----------------
__global__ __launch_bounds__(256) void qkv_proj_kernel(
    const float* __restrict__ qin, const float* __restrict__ kin,
    const float* __restrict__ vin, const float* __restrict__ W,
    const float* __restrict__ bias, unsigned short* __restrict__ q_hm,
    unsigned short* __restrict__ k_hm, unsigned short* __restrict__ v_t) {
  __shared__ __align__(16) unsigned short As[128][40];
  __shared__ __align__(16) unsigned short Bs[128][40];
  const int tid = threadIdx.x;
  const int bm = blockIdx.x;
  const int bn = blockIdx.y;
  const int z = blockIdx.z;
  const float* X = (z == 0) ? qin : (z == 1) ? kin : vin;
  const float* Wc = W + (size_t)z * E_DIM * E_DIM;
  const float* bc = bias + z * E_DIM;

  const int w = tid >> 6, lane = tid & 63;
  const int wm = w & 1, wn = w >> 1;
  const int quad = lane >> 4, l16 = lane & 15;

  f32x4 acc[4][4];
  for (int i = 0; i < 4; i++)
    for (int j = 0; j < 4; j++) { f32x4 zz = {0.f, 0.f, 0.f, 0.f}; acc[i][j] = zz; }

  const int r0 = tid >> 3;
  const int kc = (tid & 7) * 4;

  for (int k0 = 0; k0 < E_DIM; k0 += 32) {
    for (int rr = 0; rr < 4; rr++) {
      int row = r0 + rr * 32;
      float4 va = *(const float4*)&X[(size_t)(bm * 128 + row) * E_DIM + k0 + kc];
      u16x4 ha = {f2bf(va.x), f2bf(va.y), f2bf(va.z), f2bf(va.w)};
      *(u16x4*)&As[row][kc] = ha;
      float4 vb = *(const float4*)&Wc[(size_t)(bn * 128 + row) * E_DIM + k0 + kc];
      u16x4 hb = {f2bf(vb.x), f2bf(vb.y), f2bf(vb.z), f2bf(vb.w)};
      *(u16x4*)&Bs[row][kc] = hb;
    }
    __syncthreads();
    u16x8 af[4], bfv[4];
    for (int mi = 0; mi < 4; mi++)
      af[mi] = *(const u16x8*)&As[wm * 64 + mi * 16 + l16][quad * 8];
    for (int ni = 0; ni < 4; ni++)
      bfv[ni] = *(const u16x8*)&Bs[wn * 64 + ni * 16 + l16][quad * 8];
    for (int mi = 0; mi < 4; mi++)
      for (int ni = 0; ni < 4; ni++)
        acc[mi][ni] = mfma16(af[mi], bfv[ni], acc[mi][ni]);
    __syncthreads();
  }
  for (int ni = 0; ni < 4; ni++) {
    int col = bn * 128 + wn * 64 + ni * 16 + l16;
    float bv = bc[col];
    int h = col >> 6, d = col & 63;
    for (int mi = 0; mi < 4; mi++) {
      for (int r = 0; r < 4; r++) {
        int t = bm * 128 + wm * 64 + mi * 16 + quad * 4 + r;
        float v = acc[mi][ni][r] + bv;
        int nb = t & 3, pos = t >> 2;
        if (z == 0) {
          v *= 0.125f;
          q_hm[(size_t)((nb * 16 + h) * 1024 + pos) * 64 + d] = f2bf(v);
        } else if (z == 1) {
          k_hm[(size_t)((nb * 16 + h) * 1024 + pos) * 64 + d] = f2bf(v);
        } else {
          v_t[(size_t)((nb * 16 + h) * 64 + d) * 1024 + pos] = f2bf(v);
        }
      }
    }
  }
}

// ---------------- K3: attention core, m97-style pipelined ----------------
// block = (16 L rows, head b), 256 thr (4 waves). grid (64, 64).
// K and V staged to LDS via async global_load_lds (64x64 bf16 tiles, 8KB,
// double-buffered, XOR-swizzled segs). Scores A=K,B=Q -> D[s][l], softmax
// stats in registers, P (bf16) -> LDS once, PV from LDS.
__global__ __launch_bounds__(256, 3) void attn_kernel(
    const unsigned short* __restrict__ q_hm, const unsigned short* __restrict__ k_hm,
    const unsigned short* __restrict__ v_t, unsigned short* __restrict__ o_h,
    float* __restrict__ m_ws, float* __restrict__ r_ws) {
  __shared__ __align__(16) unsigned short stage[2][4096];  // 64 rows x 64 cols bf16
  __shared__ __align__(16) unsigned short sc[16][1032];    // P strip
  __shared__ float red_m[4][16];
  __shared__ float red_s[4][16];

  const int tid = threadIdx.x;
  const int l0 = blockIdx.x * 16;
  const int b = blockIdx.y;
  const int nb = b >> 4, h = b & 15;
  const int w = tid >> 6, lane = tid & 63;
  const int quad = lane >> 4, l16 = lane & 15;

  // staging: 512 segs of 16B per tile, 2 per thread; dest = seg*16 (contiguous),
  // source column-seg XOR-swizzled by row so fragment reads are conflict-free.
  const int i1 = tid + 256;
  const int r0s = tid >> 3, c0s = tid & 7;
  const int r1s = i1 >> 3, c1s = i1 & 7;
  const int src0 = (c0s ^ (r0s & 7)) * 8;
  const int src1 = (c1s ^ (r1s & 7)) * 8;

  const unsigned short* kbase = k_hm + ((size_t)b << 16);
  const unsigned short* vbase = v_t + ((size_t)b << 16);

  // ---- phase 1: scores ----
  const unsigned short* qp = q_hm + ((size_t)(b * 1024 + l0 + l16) << 6) + quad * 8;
  u16x8 bq0 = *(const u16x8*)qp;
  u16x8 bq1 = *(const u16x8*)(qp + 32);

  f32x4 acc[16];
#pragma unroll
  for (int j = 0; j < 16; j++) { f32x4 z = {0.f, 0.f, 0.f, 0.f}; acc[j] = z; }

  // K tile j: rows j*64..+64 (s), 64 d cols
  gl2lds16(kbase + ((size_t)r0s << 6) + src0, &stage[0][tid * 8]);
  gl2lds16(kbase + ((size_t)r1s << 6) + src1, &stage[0][i1 * 8]);

  const int myrow = w * 16 + l16;
  const int sw0 = ((quad ^ (l16 & 7)) * 8);
  const int sw1 = (((quad + 4) ^ (l16 & 7)) * 8);

#pragma unroll
  for (int j = 0; j < 16; j++) {
    __syncthreads();
    if (j + 1 < 16) {
      int bf = (j + 1) & 1;
      gl2lds16(kbase + ((size_t)((j + 1) * 64 + r0s) << 6) + src0, &stage[bf][tid * 8]);
      gl2lds16(kbase + ((size_t)((j + 1) * 64 + r1s) << 6) + src1, &stage[bf][i1 * 8]);
    }
    const unsigned short* kt = &stage[j & 1][myrow * 64];
    u16x8 ak0 = *(const u16x8*)(kt + sw0);
    u16x8 ak1 = *(const u16x8*)(kt + sw1);
    acc[j] = mfma16(ak0, bq0, acc[j]);
    acc[j] = mfma16(ak1, bq1, acc[j]);
  }

  // prefetch V tile 0 into buf0 (free since j=14 compute) while softmax runs
  gl2lds16(vbase + ((size_t)r0s << 10) + src0, &stage[0][tid * 8]);
  gl2lds16(vbase + ((size_t)r1s << 10) + src1, &stage[0][i1 * 8]);

  // ---- phase 2: softmax stats in registers ----
  float lm = -1e30f;
#pragma unroll
  for (int j = 0; j < 16; j++)
    for (int r = 0; r < 4; r++) lm = fmaxf(lm, acc[j][r]);
  lm = fmaxf(lm, __shfl_xor(lm, 16, 64));
  lm = fmaxf(lm, __shfl_xor(lm, 32, 64));
  if (lane < 16) red_m[w][lane] = lm;
  __syncthreads();
  float m4 = fmaxf(fmaxf(red_m[0][l16], red_m[1][l16]),
                   fmaxf(red_m[2][l16], red_m[3][l16]));

  float ls = 0.f;
#pragma unroll
  for (int j = 0; j < 16; j++) {
    float e0 = __expf(acc[j][0] - m4);
    float e1 = __expf(acc[j][1] - m4);
    float e2 = __expf(acc[j][2] - m4);
    float e3 = __expf(acc[j][3] - m4);
    ls += (e0 + e1) + (e2 + e3);
    u16x4 p = {f2bf(e0), f2bf(e1), f2bf(e2), f2bf(e3)};
    *(u16x4*)&sc[l16][j * 64 + w * 16 + quad * 4] = p;
  }
  ls += __shfl_xor(ls, 16, 64);
  ls += __shfl_xor(ls, 32, 64);
  if (lane < 16) red_s[w][lane] = ls;
  __syncthreads();
  float s4 = red_s[0][l16] + red_s[1][l16] + red_s[2][l16] + red_s[3][l16];
  float rv = 1.0f / s4;
  if (w == 0 && lane < 16) {
    m_ws[b * 1024 + l0 + lane] = m4;
    r_ws[b * 1024 + l0 + lane] = rv;
  }

  // ---- phase 3: PV from LDS (P strip x V tiles) ----
  f32x4 oacc = {0.f, 0.f, 0.f, 0.f};
  const unsigned short* scrow = &sc[l16][0];
#pragma unroll
  for (int j = 0; j < 16; j++) {
    __syncthreads();
    if (j + 1 < 16) {
      int bf = (j + 1) & 1;
      gl2lds16(vbase + ((size_t)r0s << 10) + (j + 1) * 64 + src0, &stage[bf][tid * 8]);
      gl2lds16(vbase + ((size_t)r1s << 10) + (j + 1) * 64 + src1, &stage[bf][i1 * 8]);
    }
    const unsigned short* vt = &stage[j & 1][myrow * 64];
    u16x8 bv0 = *(const u16x8*)(vt + sw0);
    u16x8 bv1 = *(const u16x8*)(vt + sw1);
    u16x8 ap0 = *(const u16x8*)(scrow + j * 64 + quad * 8);
    u16x8 ap1 = *(const u16x8*)(scrow + j * 64 + 32 + quad * 8);
    oacc = mfma16(ap0, bv0, oacc);
    oacc = mfma16(ap1, bv1, oacc);
  }

#pragma unroll
  for (int r = 0; r < 4; r++) {
    int lr = quad * 4 + r;
    float rvr = __shfl(rv, lr, 64);
    float val = oacc[r] * rvr;
    int t = (l0 + lr) * 4 + nb;
    o_h[((size_t)t << 10) + h * 64 + w * 16 + l16] = f2bf(val);
  }
}

// ---------------- K4: head-averaged attn + sigmoid weights ----------------
// sigmoid(s) = e_p * rcp(e_p + exp(-m)) reuses softmax exp -> 1 exp + 1 rcp per score.
__global__ __launch_bounds__(256) void weights_kernel(
    const unsigned short* __restrict__ q_hm, const unsigned short* __restrict__ k_hm,
    const float* __restrict__ m_ws, const float* __restrict__ r_ws,
    float* __restrict__ attn_out, float* __restrict__ sig_out) {
  const int tid = threadIdx.x;
  const int s0 = blockIdx.x * 64;
  const int l0 = blockIdx.y * 64;
  const int nb = blockIdx.z;
  const int w = tid >> 6, lane = tid & 63;
  const int quad = lane >> 4, l16 = lane & 15;
  const int lrow0 = l0 + w * 16;

  f32x4 accA[4], accS[4];
  for (int i = 0; i < 4; i++) {
    f32x4 zz = {0.f, 0.f, 0.f, 0.f};
    accA[i] = zz; accS[i] = zz;
  }

  for (int h = 0; h < 16; h++) {
    int bb = nb * 16 + h;
    const unsigned short* qp = &q_hm[((size_t)(bb * 1024 + lrow0 + l16) << 6) + quad * 8];
    u16x8 a0 = *(const u16x8*)qp;
    u16x8 a1 = *(const u16x8*)(qp + 32);
    float mv[4], rv[4], cv[4];
#pragma unroll
    for (int r = 0; r < 4; r++) {
      int l = lrow0 + quad * 4 + r;
      mv[r] = m_ws[bb * 1024 + l];
      rv[r] = r_ws[bb * 1024 + l];
      cv[r] = __expf(-mv[r]);
    }
#pragma unroll
    for (int ni = 0; ni < 4; ni++) {
      int st = s0 + ni * 16;
      const unsigned short* kp = &k_hm[((size_t)(bb * 1024 + st + l16) << 6) + quad * 8];
      u16x8 b0 = *(const u16x8*)kp;
      u16x8 b1 = *(const u16x8*)(kp + 32);
      f32x4 scv = {0.f, 0.f, 0.f, 0.f};
      scv = mfma16(a0, b0, scv);
      scv = mfma16(a1, b1, scv);
#pragma unroll
      for (int r = 0; r < 4; r++) {
        float e = __expf(scv[r] - mv[r]);
        accA[ni][r] += e * rv[r];
        accS[ni][r] += e * __builtin_amdgcn_rcpf(e + cv[r]);
      }
    }
  }
  const float inv_h = 1.0f / 16.0f;
  for (int ni = 0; ni < 4; ni++) {
    for (int r = 0; r < 4; r++) {
      int l = lrow0 + quad * 4 + r;
      int s = s0 + ni * 16 + l16;
      size_t idx = ((size_t)nb * 1024 + l) * 1024 + s;
      attn_out[idx] = accA[ni][r] * inv_h;
      sig_out[idx] = accS[ni][r] * inv_h;
    }
  }
}

// ---------------- K5: output projection ----------------
__global__ __launch_bounds__(256) void out_proj_kernel(
    const unsigned short* __restrict__ o_h, const float* __restrict__ W,
    const float* __restrict__ bias, float* __restrict__ out) {
  __shared__ __align__(16) unsigned short As[128][40];
  __shared__ __align__(16) unsigned short Bs[128][40];
  const int tid = threadIdx.x;
  const int bm = blockIdx.x, bn = blockIdx.y;
  const int w = tid >> 6, lane = tid & 63;
  const int wm = w & 1, wn = w >> 1;
  const int quad = lane >> 4, l16 = lane & 15;
  f32x4 acc[4][4];
  for (int i = 0; i < 4; i++)
    for (int j = 0; j < 4; j++) { f32x4 zz = {0.f, 0.f, 0.f, 0.f}; acc[i][j] = zz; }

  const int r0 = tid >> 3, kc = (tid & 7) * 4;
  const int ra = tid >> 2, ca = (tid & 3) * 8;

  for (int k0 = 0; k0 < E_DIM; k0 += 32) {
    for (int rr = 0; rr < 2; rr++) {
      int row = ra + rr * 64;
      u16x8 va = *(const u16x8*)&o_h[(size_t)(bm * 128 + row) * E_DIM + k0 + ca];
      *(u16x8*)&As[row][ca] = va;
    }
    for (int rr = 0; rr < 4; rr++) {
      int row = r0 + rr * 32;
      float4 vb = *(const float4*)&W[(size_t)(bn * 128 + row) * E_DIM + k0 + kc];
      u16x4 hb = {f2bf(vb.x), f2bf(vb.y), f2bf(vb.z), f2bf(vb.w)};
      *(u16x4*)&Bs[row][kc] = hb;
    }
    __syncthreads();
    u16x8 af[4], bfv[4];
    for (int mi = 0; mi < 4; mi++)
      af[mi] = *(const u16x8*)&As[wm * 64 + mi * 16 + l16][quad * 8];
    for (int ni = 0; ni < 4; ni++)
      bfv[ni] = *(const u16x8*)&Bs[wn * 64 + ni * 16 + l16][quad * 8];
    for (int mi = 0; mi < 4; mi++)
      for (int ni = 0; ni < 4; ni++)
        acc[mi][ni] = mfma16(af[mi], bfv[ni], acc[mi][ni]);
    __syncthreads();
  }
  for (int ni = 0; ni < 4; ni++) {
    int col = bn * 128 + wn * 64 + ni * 16 + l16;
    float bv = bias[col];
    for (int mi = 0; mi < 4; mi++) {
      for (int r = 0; r < 4; r++) {
        int t = bm * 128 + wm * 64 + mi * 16 + quad * 4 + r;
        out[(size_t)t * E_DIM + col] = acc[mi][ni][r] + bv;
      }
    }
  }
}

extern "C" void kernel_launch(void* const* d_in, const int* in_sizes, int n_in,
                              void* d_out, int out_size, void* d_ws, size_t ws_size,
                              hipStream_t stream) {
  const float* qin  = (const float*)d_in[0];
  const float* kin  = (const float*)d_in[1];
  const float* vin  = (const float*)d_in[2];
  const float* Wqkv = (const float*)d_in[3];
  const float* bqkv = (const float*)d_in[4];
  const float* Wout = (const float*)d_in[5];
  const float* bout = (const float*)d_in[6];
  float* out      = (float*)d_out;
  float* attn_out = out + 4194304;
  float* sig_out  = out + 8388608;

  unsigned short* q_hm = (unsigned short*)d_ws;      // [64][1024][64] bf16
  unsigned short* k_hm = q_hm + 4194304;             // [64][1024][64]
  unsigned short* v_t  = q_hm + 8388608;             // [64][64][1024]
  unsigned short* o_h  = q_hm + 12582912;            // [4096][1024]
  float* m_ws = (float*)(q_hm + 16777216);           // [64*1024]
  float* r_ws = m_ws + 65536;                        // [64*1024]

  qkv_proj_kernel<<<dim3(32, 8, 3), 256, 0, stream>>>(qin, kin, vin, Wqkv, bqkv,
                                                      q_hm, k_hm, v_t);
  attn_kernel<<<dim3(64, 64), 256, 0, stream>>>(q_hm, k_hm, v_t, o_h, m_ws, r_ws);
  weights_kernel<<<dim3(16, 16, 4), 256, 0, stream>>>(q_hm, k_hm, m_ws, r_ws,
                                                      attn_out, sig_out);
  out_proj_kernel<<<dim3(32, 8), 256, 0, stream>>>(o_h, Wout, bout, out);
}

// Round 4
// 336.787 us; speedup vs baseline: 1.2187x; 1.0941x over previous
//
#include <hip/hip_runtime.h>

// dims
#define L_DIM 1024
#define E_DIM 1024
#define NB 4
#define H_NUM 16
#define HD_DIM 64
#define T_TOK 4096   // L*NB
#define NHB 64       // NB*H_NUM

typedef float f32x4 __attribute__((ext_vector_type(4)));
typedef unsigned short u16x8 __attribute__((ext_vector_type(8)));
typedef unsigned short u16x4 __attribute__((ext_vector_type(4)));
typedef __bf16 bf16x8 __attribute__((ext_vector_type(8)));

__device__ inline unsigned short f2bf(float f) {
  unsigned int u = __builtin_bit_cast(unsigned int, f);
  u += 0x7FFFu + ((u >> 16) & 1u);
  return (unsigned short)(u >> 16);
}
__device__ inline f32x4 mfma16(u16x8 a, u16x8 b, f32x4 c) {
  return __builtin_amdgcn_mfma_f32_16x16x32_bf16(
      __builtin_bit_cast(bf16x8, a), __builtin_bit_cast(bf16x8, b), c, 0, 0, 0);
}

// async global->LDS 16B copy
__device__ __forceinline__ void gl2lds16(const void* g, void* l) {
  auto gp = reinterpret_cast<const __attribute__((address_space(1))) unsigned int*>(
      reinterpret_cast<unsigned long long>(g));
  auto lp = reinterpret_cast<__attribute__((address_space(3))) unsigned int*>(
      static_cast<unsigned int>(reinterpret_cast<unsigned long long>(l)));
  __builtin_amdgcn_global_load_lds(gp, lp, 16, 0, 0);
}

// ---------------- K1: packed QKV projection ----------------
__global__ __launch_bounds__(256) void qkv_proj_kernel(
    const float* __restrict__ qin, const float* __restrict__ kin,
    const float* __restrict__ vin, const float* __restrict__ W,
    const float* __restrict__ bias, unsigned short* __restrict__ q_hm,
    unsigned short* __restrict__ k_hm, unsigned short* __restrict__ v_t) {
  __shared__ __align__(16) unsigned short As[128][40];
  __shared__ __align__(16) unsigned short Bs[128][40];
  const int tid = threadIdx.x;
  const int bm = blockIdx.x;
  const int bn = blockIdx.y;
  const int z = blockIdx.z;
  const float* X = (z == 0) ? qin : (z == 1) ? kin : vin;
  const float* Wc = W + (size_t)z * E_DIM * E_DIM;
  const float* bc = bias + z * E_DIM;

  const int w = tid >> 6, lane = tid & 63;
  const int wm = w & 1, wn = w >> 1;
  const int quad = lane >> 4, l16 = lane & 15;

  f32x4 acc[4][4];
  for (int i = 0; i < 4; i++)
    for (int j = 0; j < 4; j++) { f32x4 zz = {0.f, 0.f, 0.f, 0.f}; acc[i][j] = zz; }

  const int r0 = tid >> 3;
  const int kc = (tid & 7) * 4;

  for (int k0 = 0; k0 < E_DIM; k0 += 32) {
    for (int rr = 0; rr < 4; rr++) {
      int row = r0 + rr * 32;
      float4 va = *(const float4*)&X[(size_t)(bm * 128 + row) * E_DIM + k0 + kc];
      u16x4 ha = {f2bf(va.x), f2bf(va.y), f2bf(va.z), f2bf(va.w)};
      *(u16x4*)&As[row][kc] = ha;
      float4 vb = *(const float4*)&Wc[(size_t)(bn * 128 + row) * E_DIM + k0 + kc];
      u16x4 hb = {f2bf(vb.x), f2bf(vb.y), f2bf(vb.z), f2bf(vb.w)};
      *(u16x4*)&Bs[row][kc] = hb;
    }
    __syncthreads();
    u16x8 af[4], bfv[4];
    for (int mi = 0; mi < 4; mi++)
      af[mi] = *(const u16x8*)&As[wm * 64 + mi * 16 + l16][quad * 8];
    for (int ni = 0; ni < 4; ni++)
      bfv[ni] = *(const u16x8*)&Bs[wn * 64 + ni * 16 + l16][quad * 8];
    for (int mi = 0; mi < 4; mi++)
      for (int ni = 0; ni < 4; ni++)
        acc[mi][ni] = mfma16(af[mi], bfv[ni], acc[mi][ni]);
    __syncthreads();
  }
  for (int ni = 0; ni < 4; ni++) {
    int col = bn * 128 + wn * 64 + ni * 16 + l16;
    float bv = bc[col];
    int h = col >> 6, d = col & 63;
    for (int mi = 0; mi < 4; mi++) {
      for (int r = 0; r < 4; r++) {
        int t = bm * 128 + wm * 64 + mi * 16 + quad * 4 + r;
        float v = acc[mi][ni][r] + bv;
        int nb = t & 3, pos = t >> 2;
        if (z == 0) {
          v *= 0.125f;
          q_hm[(size_t)((nb * 16 + h) * 1024 + pos) * 64 + d] = f2bf(v);
        } else if (z == 1) {
          k_hm[(size_t)((nb * 16 + h) * 1024 + pos) * 64 + d] = f2bf(v);
        } else {
          v_t[(size_t)((nb * 16 + h) * 64 + d) * 1024 + pos] = f2bf(v);
        }
      }
    }
  }
}

// ---------------- K3: attention core, m97-style pipelined ----------------
__global__ __launch_bounds__(256, 3) void attn_kernel(
    const unsigned short* __restrict__ q_hm, const unsigned short* __restrict__ k_hm,
    const unsigned short* __restrict__ v_t, unsigned short* __restrict__ o_h,
    float* __restrict__ m_ws, float* __restrict__ r_ws) {
  __shared__ __align__(16) unsigned short stage[2][4096];
  __shared__ __align__(16) unsigned short sc[16][1032];
  __shared__ float red_m[4][16];
  __shared__ float red_s[4][16];

  const int tid = threadIdx.x;
  const int l0 = blockIdx.x * 16;
  const int b = blockIdx.y;
  const int nb = b >> 4, h = b & 15;
  const int w = tid >> 6, lane = tid & 63;
  const int quad = lane >> 4, l16 = lane & 15;

  const int i1 = tid + 256;
  const int r0s = tid >> 3, c0s = tid & 7;
  const int r1s = i1 >> 3, c1s = i1 & 7;
  const int src0 = (c0s ^ (r0s & 7)) * 8;
  const int src1 = (c1s ^ (r1s & 7)) * 8;

  const unsigned short* kbase = k_hm + ((size_t)b << 16);
  const unsigned short* vbase = v_t + ((size_t)b << 16);

  const unsigned short* qp = q_hm + ((size_t)(b * 1024 + l0 + l16) << 6) + quad * 8;
  u16x8 bq0 = *(const u16x8*)qp;
  u16x8 bq1 = *(const u16x8*)(qp + 32);

  f32x4 acc[16];
#pragma unroll
  for (int j = 0; j < 16; j++) { f32x4 z = {0.f, 0.f, 0.f, 0.f}; acc[j] = z; }

  gl2lds16(kbase + ((size_t)r0s << 6) + src0, &stage[0][tid * 8]);
  gl2lds16(kbase + ((size_t)r1s << 6) + src1, &stage[0][i1 * 8]);

  const int myrow = w * 16 + l16;
  const int sw0 = ((quad ^ (l16 & 7)) * 8);
  const int sw1 = (((quad + 4) ^ (l16 & 7)) * 8);

#pragma unroll
  for (int j = 0; j < 16; j++) {
    __syncthreads();
    if (j + 1 < 16) {
      int bf = (j + 1) & 1;
      gl2lds16(kbase + ((size_t)((j + 1) * 64 + r0s) << 6) + src0, &stage[bf][tid * 8]);
      gl2lds16(kbase + ((size_t)((j + 1) * 64 + r1s) << 6) + src1, &stage[bf][i1 * 8]);
    }
    const unsigned short* kt = &stage[j & 1][myrow * 64];
    u16x8 ak0 = *(const u16x8*)(kt + sw0);
    u16x8 ak1 = *(const u16x8*)(kt + sw1);
    acc[j] = mfma16(ak0, bq0, acc[j]);
    acc[j] = mfma16(ak1, bq1, acc[j]);
  }

  gl2lds16(vbase + ((size_t)r0s << 10) + src0, &stage[0][tid * 8]);
  gl2lds16(vbase + ((size_t)r1s << 10) + src1, &stage[0][i1 * 8]);

  float lm = -1e30f;
#pragma unroll
  for (int j = 0; j < 16; j++)
    for (int r = 0; r < 4; r++) lm = fmaxf(lm, acc[j][r]);
  lm = fmaxf(lm, __shfl_xor(lm, 16, 64));
  lm = fmaxf(lm, __shfl_xor(lm, 32, 64));
  if (lane < 16) red_m[w][lane] = lm;
  __syncthreads();
  float m4 = fmaxf(fmaxf(red_m[0][l16], red_m[1][l16]),
                   fmaxf(red_m[2][l16], red_m[3][l16]));

  float ls = 0.f;
#pragma unroll
  for (int j = 0; j < 16; j++) {
    float e0 = __expf(acc[j][0] - m4);
    float e1 = __expf(acc[j][1] - m4);
    float e2 = __expf(acc[j][2] - m4);
    float e3 = __expf(acc[j][3] - m4);
    ls += (e0 + e1) + (e2 + e3);
    u16x4 p = {f2bf(e0), f2bf(e1), f2bf(e2), f2bf(e3)};
    *(u16x4*)&sc[l16][j * 64 + w * 16 + quad * 4] = p;
  }
  ls += __shfl_xor(ls, 16, 64);
  ls += __shfl_xor(ls, 32, 64);
  if (lane < 16) red_s[w][lane] = ls;
  __syncthreads();
  float s4 = red_s[0][l16] + red_s[1][l16] + red_s[2][l16] + red_s[3][l16];
  float rv = 1.0f / s4;
  if (w == 0 && lane < 16) {
    m_ws[b * 1024 + l0 + lane] = m4;
    r_ws[b * 1024 + l0 + lane] = rv;
  }

  f32x4 oacc = {0.f, 0.f, 0.f, 0.f};
  const unsigned short* scrow = &sc[l16][0];
#pragma unroll
  for (int j = 0; j < 16; j++) {
    __syncthreads();
    if (j + 1 < 16) {
      int bf = (j + 1) & 1;
      gl2lds16(vbase + ((size_t)r0s << 10) + (j + 1) * 64 + src0, &stage[bf][tid * 8]);
      gl2lds16(vbase + ((size_t)r1s << 10) + (j + 1) * 64 + src1, &stage[bf][i1 * 8]);
    }
    const unsigned short* vt = &stage[j & 1][myrow * 64];
    u16x8 bv0 = *(const u16x8*)(vt + sw0);
    u16x8 bv1 = *(const u16x8*)(vt + sw1);
    u16x8 ap0 = *(const u16x8*)(scrow + j * 64 + quad * 8);
    u16x8 ap1 = *(const u16x8*)(scrow + j * 64 + 32 + quad * 8);
    oacc = mfma16(ap0, bv0, oacc);
    oacc = mfma16(ap1, bv1, oacc);
  }

#pragma unroll
  for (int r = 0; r < 4; r++) {
    int lr = quad * 4 + r;
    float rvr = __shfl(rv, lr, 64);
    float val = oacc[r] * rvr;
    int t = (l0 + lr) * 4 + nb;
    o_h[((size_t)t << 10) + h * 64 + w * 16 + l16] = f2bf(val);
  }
}

// ---------------- K4: head-averaged attn + sigmoid weights ----------------
// LDS-pipelined over heads: Q/K 64x64 tiles double-buffered via global_load_lds,
// m/r/cv staged once. sigmoid(s) = e * rcp(e + exp(-m)) reuses softmax exp.
__global__ __launch_bounds__(256) void weights_kernel(
    const unsigned short* __restrict__ q_hm, const unsigned short* __restrict__ k_hm,
    const float* __restrict__ m_ws, const float* __restrict__ r_ws,
    float* __restrict__ attn_out, float* __restrict__ sig_out) {
  __shared__ __align__(16) unsigned short qs[2][4096];
  __shared__ __align__(16) unsigned short ks[2][4096];
  __shared__ float ml[16][64];
  __shared__ float rl[16][64];
  __shared__ float cl[16][64];

  const int tid = threadIdx.x;
  const int s0 = blockIdx.x * 64;
  const int l0 = blockIdx.y * 64;
  const int nb = blockIdx.z;
  const int w = tid >> 6, lane = tid & 63;
  const int quad = lane >> 4, l16 = lane & 15;

  // staging geometry (XOR-swizzled 16B segs, same as attn_kernel)
  const int i1 = tid + 256;
  const int r0s = tid >> 3, c0s = tid & 7;
  const int r1s = i1 >> 3, c1s = i1 & 7;
  const int src0 = (c0s ^ (r0s & 7)) * 8;
  const int src1 = (c1s ^ (r1s & 7)) * 8;

  // stage m/r/cv for all 16 heads x 64 l-rows (4 entries per thread)
  {
    int idx = tid * 4;
    int hh = idx >> 6, ii = idx & 63;
    int bb = nb * 16 + hh;
    float4 mv4 = *(const float4*)&m_ws[bb * 1024 + l0 + ii];
    float4 rv4 = *(const float4*)&r_ws[bb * 1024 + l0 + ii];
    *(float4*)&ml[hh][ii] = mv4;
    *(float4*)&rl[hh][ii] = rv4;
    float4 cv4 = {__expf(-mv4.x), __expf(-mv4.y), __expf(-mv4.z), __expf(-mv4.w)};
    *(float4*)&cl[hh][ii] = cv4;
  }

  // prefetch head 0
  {
    int bb = nb * 16;
    const unsigned short* qb = q_hm + ((size_t)(bb * 1024 + l0) << 6);
    const unsigned short* kb = k_hm + ((size_t)(bb * 1024 + s0) << 6);
    gl2lds16(qb + (r0s << 6) + src0, &qs[0][tid * 8]);
    gl2lds16(qb + (r1s << 6) + src1, &qs[0][i1 * 8]);
    gl2lds16(kb + (r0s << 6) + src0, &ks[0][tid * 8]);
    gl2lds16(kb + (r1s << 6) + src1, &ks[0][i1 * 8]);
  }

  const int sw0 = ((quad ^ (l16 & 7)) * 8);
  const int sw1 = (((quad + 4) ^ (l16 & 7)) * 8);

  f32x4 accA[4], accS[4];
#pragma unroll
  for (int i = 0; i < 4; i++) {
    f32x4 zz = {0.f, 0.f, 0.f, 0.f};
    accA[i] = zz; accS[i] = zz;
  }

#pragma unroll
  for (int h = 0; h < 16; h++) {
    __syncthreads();
    if (h + 1 < 16) {
      int bf = (h + 1) & 1;
      int bb = nb * 16 + h + 1;
      const unsigned short* qb = q_hm + ((size_t)(bb * 1024 + l0) << 6);
      const unsigned short* kb = k_hm + ((size_t)(bb * 1024 + s0) << 6);
      gl2lds16(qb + (r0s << 6) + src0, &qs[bf][tid * 8]);
      gl2lds16(qb + (r1s << 6) + src1, &qs[bf][i1 * 8]);
      gl2lds16(kb + (r0s << 6) + src0, &ks[bf][tid * 8]);
      gl2lds16(kb + (r1s << 6) + src1, &ks[bf][i1 * 8]);
    }
    const int bf = h & 1;
    const unsigned short* qt = &qs[bf][(w * 16 + l16) * 64];
    u16x8 a0 = *(const u16x8*)(qt + sw0);
    u16x8 a1 = *(const u16x8*)(qt + sw1);
    f32x4 mv = *(const f32x4*)&ml[h][w * 16 + quad * 4];
    f32x4 rv = *(const f32x4*)&rl[h][w * 16 + quad * 4];
    f32x4 cv = *(const f32x4*)&cl[h][w * 16 + quad * 4];
#pragma unroll
    for (int ni = 0; ni < 4; ni++) {
      const unsigned short* kt = &ks[bf][(ni * 16 + l16) * 64];
      u16x8 b0 = *(const u16x8*)(kt + sw0);
      u16x8 b1 = *(const u16x8*)(kt + sw1);
      f32x4 scv = {0.f, 0.f, 0.f, 0.f};
      scv = mfma16(a0, b0, scv);
      scv = mfma16(a1, b1, scv);
#pragma unroll
      for (int r = 0; r < 4; r++) {
        float e = __expf(scv[r] - mv[r]);
        accA[ni][r] += e * rv[r];
        accS[ni][r] += e * __builtin_amdgcn_rcpf(e + cv[r]);
      }
    }
  }
  const float inv_h = 1.0f / 16.0f;
  const int lrow0 = l0 + w * 16;
#pragma unroll
  for (int ni = 0; ni < 4; ni++) {
#pragma unroll
    for (int r = 0; r < 4; r++) {
      int l = lrow0 + quad * 4 + r;
      int s = s0 + ni * 16 + l16;
      size_t idx = ((size_t)nb * 1024 + l) * 1024 + s;
      attn_out[idx] = accA[ni][r] * inv_h;
      sig_out[idx] = accS[ni][r] * inv_h;
    }
  }
}

// ---------------- K5: output projection ----------------
__global__ __launch_bounds__(256) void out_proj_kernel(
    const unsigned short* __restrict__ o_h, const float* __restrict__ W,
    const float* __restrict__ bias, float* __restrict__ out) {
  __shared__ __align__(16) unsigned short As[128][40];
  __shared__ __align__(16) unsigned short Bs[128][40];
  const int tid = threadIdx.x;
  const int bm = blockIdx.x, bn = blockIdx.y;
  const int w = tid >> 6, lane = tid & 63;
  const int wm = w & 1, wn = w >> 1;
  const int quad = lane >> 4, l16 = lane & 15;
  f32x4 acc[4][4];
  for (int i = 0; i < 4; i++)
    for (int j = 0; j < 4; j++) { f32x4 zz = {0.f, 0.f, 0.f, 0.f}; acc[i][j] = zz; }

  const int r0 = tid >> 3, kc = (tid & 7) * 4;
  const int ra = tid >> 2, ca = (tid & 3) * 8;

  for (int k0 = 0; k0 < E_DIM; k0 += 32) {
    for (int rr = 0; rr < 2; rr++) {
      int row = ra + rr * 64;
      u16x8 va = *(const u16x8*)&o_h[(size_t)(bm * 128 + row) * E_DIM + k0 + ca];
      *(u16x8*)&As[row][ca] = va;
    }
    for (int rr = 0; rr < 4; rr++) {
      int row = r0 + rr * 32;
      float4 vb = *(const float4*)&W[(size_t)(bn * 128 + row) * E_DIM + k0 + kc];
      u16x4 hb = {f2bf(vb.x), f2bf(vb.y), f2bf(vb.z), f2bf(vb.w)};
      *(u16x4*)&Bs[row][kc] = hb;
    }
    __syncthreads();
    u16x8 af[4], bfv[4];
    for (int mi = 0; mi < 4; mi++)
      af[mi] = *(const u16x8*)&As[wm * 64 + mi * 16 + l16][quad * 8];
    for (int ni = 0; ni < 4; ni++)
      bfv[ni] = *(const u16x8*)&Bs[wn * 64 + ni * 16 + l16][quad * 8];
    for (int mi = 0; mi < 4; mi++)
      for (int ni = 0; ni < 4; ni++)
        acc[mi][ni] = mfma16(af[mi], bfv[ni], acc[mi][ni]);
    __syncthreads();
  }
  for (int ni = 0; ni < 4; ni++) {
    int col = bn * 128 + wn * 64 + ni * 16 + l16;
    float bv = bias[col];
    for (int mi = 0; mi < 4; mi++) {
      for (int r = 0; r < 4; r++) {
        int t = bm * 128 + wm * 64 + mi * 16 + quad * 4 + r;
        out[(size_t)t * E_DIM + col] = acc[mi][ni][r] + bv;
      }
    }
  }
}

extern "C" void kernel_launch(void* const* d_in, const int* in_sizes, int n_in,
                              void* d_out, int out_size, void* d_ws, size_t ws_size,
                              hipStream_t stream) {
  const float* qin  = (const float*)d_in[0];
  const float* kin  = (const float*)d_in[1];
  const float* vin  = (const float*)d_in[2];
  const float* Wqkv = (const float*)d_in[3];
  const float* bqkv = (const float*)d_in[4];
  const float* Wout = (const float*)d_in[5];
  const float* bout = (const float*)d_in[6];
  float* out      = (float*)d_out;
  float* attn_out = out + 4194304;
  float* sig_out  = out + 8388608;

  unsigned short* q_hm = (unsigned short*)d_ws;      // [64][1024][64] bf16
  unsigned short* k_hm = q_hm + 4194304;             // [64][1024][64]
  unsigned short* v_t  = q_hm + 8388608;             // [64][64][1024]
  unsigned short* o_h  = q_hm + 12582912;            // [4096][1024]
  float* m_ws = (float*)(q_hm + 16777216);           // [64*1024]
  float* r_ws = m_ws + 65536;                        // [64*1024]

  qkv_proj_kernel<<<dim3(32, 8, 3), 256, 0, stream>>>(qin, kin, vin, Wqkv, bqkv,
                                                      q_hm, k_hm, v_t);
  attn_kernel<<<dim3(64, 64), 256, 0, stream>>>(q_hm, k_hm, v_t, o_h, m_ws, r_ws);
  weights_kernel<<<dim3(16, 16, 4), 256, 0, stream>>>(q_hm, k_hm, m_ws, r_ws,
                                                      attn_out, sig_out);
  out_proj_kernel<<<dim3(32, 8), 256, 0, stream>>>(o_h, Wout, bout, out);
}

// Round 5
// 306.641 us; speedup vs baseline: 1.3385x; 1.0983x over previous
//
#include <hip/hip_runtime.h>

// dims
#define L_DIM 1024
#define E_DIM 1024
#define NB 4
#define H_NUM 16
#define HD_DIM 64
#define T_TOK 4096   // L*NB
#define NHB 64       // NB*H_NUM

typedef float f32x4 __attribute__((ext_vector_type(4)));
typedef unsigned short u16x8 __attribute__((ext_vector_type(8)));
typedef unsigned short u16x4 __attribute__((ext_vector_type(4)));
typedef __bf16 bf16x8 __attribute__((ext_vector_type(8)));

__device__ inline unsigned short f2bf(float f) {
  unsigned int u = __builtin_bit_cast(unsigned int, f);
  u += 0x7FFFu + ((u >> 16) & 1u);
  return (unsigned short)(u >> 16);
}
__device__ inline f32x4 mfma16(u16x8 a, u16x8 b, f32x4 c) {
  return __builtin_amdgcn_mfma_f32_16x16x32_bf16(
      __builtin_bit_cast(bf16x8, a), __builtin_bit_cast(bf16x8, b), c, 0, 0, 0);
}

// async global->LDS 16B copy
__device__ __forceinline__ void gl2lds16(const void* g, void* l) {
  auto gp = reinterpret_cast<const __attribute__((address_space(1))) unsigned int*>(
      reinterpret_cast<unsigned long long>(g));
  auto lp = reinterpret_cast<__attribute__((address_space(3))) unsigned int*>(
      static_cast<unsigned int>(reinterpret_cast<unsigned long long>(l)));
  __builtin_amdgcn_global_load_lds(gp, lp, 16, 0, 0);
}

// ---------------- K0: f32 -> bf16 cast (up to 4 arrays per launch) ----------------
__global__ __launch_bounds__(256) void cast_kernel(
    const float* __restrict__ s0, const float* __restrict__ s1,
    const float* __restrict__ s2, const float* __restrict__ s3,
    unsigned short* __restrict__ d0, unsigned short* __restrict__ d1,
    unsigned short* __restrict__ d2, unsigned short* __restrict__ d3,
    int n0, int n1, int n2, int n3) {
  const int y = blockIdx.y;
  const float* s = (y == 0) ? s0 : (y == 1) ? s1 : (y == 2) ? s2 : s3;
  unsigned short* d = (y == 0) ? d0 : (y == 1) ? d1 : (y == 2) ? d2 : d3;
  const int n = (y == 0) ? n0 : (y == 1) ? n1 : (y == 2) ? n2 : n3;
  int idx = (blockIdx.x * 256 + threadIdx.x) * 8;
  const int stride = gridDim.x * 256 * 8;
  for (; idx < n; idx += stride) {
    float4 a = *(const float4*)(s + idx);
    float4 b = *(const float4*)(s + idx + 4);
    u16x8 o = {f2bf(a.x), f2bf(a.y), f2bf(a.z), f2bf(a.w),
               f2bf(b.x), f2bf(b.y), f2bf(b.z), f2bf(b.w)};
    *(u16x8*)(d + idx) = o;
  }
}

// ---- shared GEMM staging: 128 rows x 32 k bf16 tile (8 KB), swizzled ----
// seg (r, c): LDS offset (r*4+c)*16B holds global k-chunk (c ^ ((r^(r>>2))&3)).
__device__ __forceinline__ void stage_tile(const unsigned short* __restrict__ g,
                                           unsigned short* lbuf, int tid) {
  const int r = tid >> 2, c = tid & 3;
  const int sc = c ^ ((r ^ (r >> 2)) & 3);
  gl2lds16(g + (size_t)r * 1024 + sc * 8, lbuf + tid * 8);
  const int r2 = r + 64;
  gl2lds16(g + (size_t)r2 * 1024 + sc * 8, lbuf + (tid + 256) * 8);
}
// fragment read offset (u16 units) for row r, k-chunk q
__device__ __forceinline__ int frag_off(int r, int q) {
  return r * 32 + ((q ^ ((r ^ (r >> 2)) & 3)) << 3);
}

// ---------------- K1: packed QKV projection (bf16 in, m97-style) ----------------
// grid (32 m-tiles, 8 n-tiles, 3 chunks), block 256
__global__ __launch_bounds__(256) void qkv_gemm(
    const unsigned short* __restrict__ qb, const unsigned short* __restrict__ kb,
    const unsigned short* __restrict__ vb, const unsigned short* __restrict__ Wb,
    const float* __restrict__ bias, unsigned short* __restrict__ q_hm,
    unsigned short* __restrict__ k_hm, unsigned short* __restrict__ v_t) {
  __shared__ __align__(16) unsigned short As[2][4096];
  __shared__ __align__(16) unsigned short Bs[2][4096];
  const int tid = threadIdx.x;
  const int bm = blockIdx.x, bn = blockIdx.y, z = blockIdx.z;
  const unsigned short* Ag = ((z == 0) ? qb : (z == 1) ? kb : vb) + (size_t)bm * 128 * 1024;
  const unsigned short* Bg = Wb + (size_t)z * 1048576 + (size_t)bn * 128 * 1024;
  const float* bc = bias + z * E_DIM;

  const int w = tid >> 6, lane = tid & 63;
  const int wm = w & 1, wn = w >> 1;
  const int quad = lane >> 4, l16 = lane & 15;

  f32x4 acc[4][4];
#pragma unroll
  for (int i = 0; i < 4; i++)
#pragma unroll
    for (int j = 0; j < 4; j++) { f32x4 zz = {0.f, 0.f, 0.f, 0.f}; acc[i][j] = zz; }

  stage_tile(Ag, As[0], tid);
  stage_tile(Bg, Bs[0], tid);

  for (int kk = 0; kk < 32; kk++) {
    __syncthreads();
    if (kk + 1 < 32) {
      const int bf = (kk + 1) & 1;
      stage_tile(Ag + (kk + 1) * 32, As[bf], tid);
      stage_tile(Bg + (kk + 1) * 32, Bs[bf], tid);
    }
    const int cb = kk & 1;
    u16x8 af[4], bfv[4];
#pragma unroll
    for (int mi = 0; mi < 4; mi++) {
      int r = wm * 64 + mi * 16 + l16;
      af[mi] = *(const u16x8*)&As[cb][frag_off(r, quad)];
    }
#pragma unroll
    for (int ni = 0; ni < 4; ni++) {
      int r = wn * 64 + ni * 16 + l16;
      bfv[ni] = *(const u16x8*)&Bs[cb][frag_off(r, quad)];
    }
#pragma unroll
    for (int mi = 0; mi < 4; mi++)
#pragma unroll
      for (int ni = 0; ni < 4; ni++)
        acc[mi][ni] = mfma16(af[mi], bfv[ni], acc[mi][ni]);
  }
#pragma unroll
  for (int ni = 0; ni < 4; ni++) {
    int col = bn * 128 + wn * 64 + ni * 16 + l16;
    float bv = bc[col];
    int h = col >> 6, d = col & 63;
#pragma unroll
    for (int mi = 0; mi < 4; mi++) {
#pragma unroll
      for (int r = 0; r < 4; r++) {
        int t = bm * 128 + wm * 64 + mi * 16 + quad * 4 + r;
        float v = acc[mi][ni][r] + bv;
        int nb = t & 3, pos = t >> 2;
        if (z == 0) {
          v *= 0.125f;
          q_hm[(size_t)((nb * 16 + h) * 1024 + pos) * 64 + d] = f2bf(v);
        } else if (z == 1) {
          k_hm[(size_t)((nb * 16 + h) * 1024 + pos) * 64 + d] = f2bf(v);
        } else {
          v_t[(size_t)((nb * 16 + h) * 64 + d) * 1024 + pos] = f2bf(v);
        }
      }
    }
  }
}

// ---------------- K3: attention core, m97-style pipelined (unchanged) ----------------
__global__ __launch_bounds__(256, 3) void attn_kernel(
    const unsigned short* __restrict__ q_hm, const unsigned short* __restrict__ k_hm,
    const unsigned short* __restrict__ v_t, unsigned short* __restrict__ o_h,
    float* __restrict__ m_ws, float* __restrict__ r_ws) {
  __shared__ __align__(16) unsigned short stage[2][4096];
  __shared__ __align__(16) unsigned short sc[16][1032];
  __shared__ float red_m[4][16];
  __shared__ float red_s[4][16];

  const int tid = threadIdx.x;
  const int l0 = blockIdx.x * 16;
  const int b = blockIdx.y;
  const int nb = b >> 4, h = b & 15;
  const int w = tid >> 6, lane = tid & 63;
  const int quad = lane >> 4, l16 = lane & 15;

  const int i1 = tid + 256;
  const int r0s = tid >> 3, c0s = tid & 7;
  const int r1s = i1 >> 3, c1s = i1 & 7;
  const int src0 = (c0s ^ (r0s & 7)) * 8;
  const int src1 = (c1s ^ (r1s & 7)) * 8;

  const unsigned short* kbase = k_hm + ((size_t)b << 16);
  const unsigned short* vbase = v_t + ((size_t)b << 16);

  const unsigned short* qp = q_hm + ((size_t)(b * 1024 + l0 + l16) << 6) + quad * 8;
  u16x8 bq0 = *(const u16x8*)qp;
  u16x8 bq1 = *(const u16x8*)(qp + 32);

  f32x4 acc[16];
#pragma unroll
  for (int j = 0; j < 16; j++) { f32x4 z = {0.f, 0.f, 0.f, 0.f}; acc[j] = z; }

  gl2lds16(kbase + ((size_t)r0s << 6) + src0, &stage[0][tid * 8]);
  gl2lds16(kbase + ((size_t)r1s << 6) + src1, &stage[0][i1 * 8]);

  const int myrow = w * 16 + l16;
  const int sw0 = ((quad ^ (l16 & 7)) * 8);
  const int sw1 = (((quad + 4) ^ (l16 & 7)) * 8);

#pragma unroll
  for (int j = 0; j < 16; j++) {
    __syncthreads();
    if (j + 1 < 16) {
      int bf = (j + 1) & 1;
      gl2lds16(kbase + ((size_t)((j + 1) * 64 + r0s) << 6) + src0, &stage[bf][tid * 8]);
      gl2lds16(kbase + ((size_t)((j + 1) * 64 + r1s) << 6) + src1, &stage[bf][i1 * 8]);
    }
    const unsigned short* kt = &stage[j & 1][myrow * 64];
    u16x8 ak0 = *(const u16x8*)(kt + sw0);
    u16x8 ak1 = *(const u16x8*)(kt + sw1);
    acc[j] = mfma16(ak0, bq0, acc[j]);
    acc[j] = mfma16(ak1, bq1, acc[j]);
  }

  gl2lds16(vbase + ((size_t)r0s << 10) + src0, &stage[0][tid * 8]);
  gl2lds16(vbase + ((size_t)r1s << 10) + src1, &stage[0][i1 * 8]);

  float lm = -1e30f;
#pragma unroll
  for (int j = 0; j < 16; j++)
    for (int r = 0; r < 4; r++) lm = fmaxf(lm, acc[j][r]);
  lm = fmaxf(lm, __shfl_xor(lm, 16, 64));
  lm = fmaxf(lm, __shfl_xor(lm, 32, 64));
  if (lane < 16) red_m[w][lane] = lm;
  __syncthreads();
  float m4 = fmaxf(fmaxf(red_m[0][l16], red_m[1][l16]),
                   fmaxf(red_m[2][l16], red_m[3][l16]));

  float ls = 0.f;
#pragma unroll
  for (int j = 0; j < 16; j++) {
    float e0 = __expf(acc[j][0] - m4);
    float e1 = __expf(acc[j][1] - m4);
    float e2 = __expf(acc[j][2] - m4);
    float e3 = __expf(acc[j][3] - m4);
    ls += (e0 + e1) + (e2 + e3);
    u16x4 p = {f2bf(e0), f2bf(e1), f2bf(e2), f2bf(e3)};
    *(u16x4*)&sc[l16][j * 64 + w * 16 + quad * 4] = p;
  }
  ls += __shfl_xor(ls, 16, 64);
  ls += __shfl_xor(ls, 32, 64);
  if (lane < 16) red_s[w][lane] = ls;
  __syncthreads();
  float s4 = red_s[0][l16] + red_s[1][l16] + red_s[2][l16] + red_s[3][l16];
  float rv = 1.0f / s4;
  if (w == 0 && lane < 16) {
    m_ws[b * 1024 + l0 + lane] = m4;
    r_ws[b * 1024 + l0 + lane] = rv;
  }

  f32x4 oacc = {0.f, 0.f, 0.f, 0.f};
  const unsigned short* scrow = &sc[l16][0];
#pragma unroll
  for (int j = 0; j < 16; j++) {
    __syncthreads();
    if (j + 1 < 16) {
      int bf = (j + 1) & 1;
      gl2lds16(vbase + ((size_t)r0s << 10) + (j + 1) * 64 + src0, &stage[bf][tid * 8]);
      gl2lds16(vbase + ((size_t)r1s << 10) + (j + 1) * 64 + src1, &stage[bf][i1 * 8]);
    }
    const unsigned short* vt = &stage[j & 1][myrow * 64];
    u16x8 bv0 = *(const u16x8*)(vt + sw0);
    u16x8 bv1 = *(const u16x8*)(vt + sw1);
    u16x8 ap0 = *(const u16x8*)(scrow + j * 64 + quad * 8);
    u16x8 ap1 = *(const u16x8*)(scrow + j * 64 + 32 + quad * 8);
    oacc = mfma16(ap0, bv0, oacc);
    oacc = mfma16(ap1, bv1, oacc);
  }

#pragma unroll
  for (int r = 0; r < 4; r++) {
    int lr = quad * 4 + r;
    float rvr = __shfl(rv, lr, 64);
    float val = oacc[r] * rvr;
    int t = (l0 + lr) * 4 + nb;
    o_h[((size_t)t << 10) + h * 64 + w * 16 + l16] = f2bf(val);
  }
}

// ---------------- K4: head-averaged attn + sigmoid weights (unchanged) ----------------
__global__ __launch_bounds__(256) void weights_kernel(
    const unsigned short* __restrict__ q_hm, const unsigned short* __restrict__ k_hm,
    const float* __restrict__ m_ws, const float* __restrict__ r_ws,
    float* __restrict__ attn_out, float* __restrict__ sig_out) {
  __shared__ __align__(16) unsigned short qs[2][4096];
  __shared__ __align__(16) unsigned short ks[2][4096];
  __shared__ float ml[16][64];
  __shared__ float rl[16][64];
  __shared__ float cl[16][64];

  const int tid = threadIdx.x;
  const int s0 = blockIdx.x * 64;
  const int l0 = blockIdx.y * 64;
  const int nb = blockIdx.z;
  const int w = tid >> 6, lane = tid & 63;
  const int quad = lane >> 4, l16 = lane & 15;

  const int i1 = tid + 256;
  const int r0s = tid >> 3, c0s = tid & 7;
  const int r1s = i1 >> 3, c1s = i1 & 7;
  const int src0 = (c0s ^ (r0s & 7)) * 8;
  const int src1 = (c1s ^ (r1s & 7)) * 8;

  {
    int idx = tid * 4;
    int hh = idx >> 6, ii = idx & 63;
    int bb = nb * 16 + hh;
    float4 mv4 = *(const float4*)&m_ws[bb * 1024 + l0 + ii];
    float4 rv4 = *(const float4*)&r_ws[bb * 1024 + l0 + ii];
    *(float4*)&ml[hh][ii] = mv4;
    *(float4*)&rl[hh][ii] = rv4;
    float4 cv4 = {__expf(-mv4.x), __expf(-mv4.y), __expf(-mv4.z), __expf(-mv4.w)};
    *(float4*)&cl[hh][ii] = cv4;
  }

  {
    int bb = nb * 16;
    const unsigned short* qb = q_hm + ((size_t)(bb * 1024 + l0) << 6);
    const unsigned short* kb = k_hm + ((size_t)(bb * 1024 + s0) << 6);
    gl2lds16(qb + (r0s << 6) + src0, &qs[0][tid * 8]);
    gl2lds16(qb + (r1s << 6) + src1, &qs[0][i1 * 8]);
    gl2lds16(kb + (r0s << 6) + src0, &ks[0][tid * 8]);
    gl2lds16(kb + (r1s << 6) + src1, &ks[0][i1 * 8]);
  }

  const int sw0 = ((quad ^ (l16 & 7)) * 8);
  const int sw1 = (((quad + 4) ^ (l16 & 7)) * 8);

  f32x4 accA[4], accS[4];
#pragma unroll
  for (int i = 0; i < 4; i++) {
    f32x4 zz = {0.f, 0.f, 0.f, 0.f};
    accA[i] = zz; accS[i] = zz;
  }

#pragma unroll
  for (int h = 0; h < 16; h++) {
    __syncthreads();
    if (h + 1 < 16) {
      int bf = (h + 1) & 1;
      int bb = nb * 16 + h + 1;
      const unsigned short* qb = q_hm + ((size_t)(bb * 1024 + l0) << 6);
      const unsigned short* kb = k_hm + ((size_t)(bb * 1024 + s0) << 6);
      gl2lds16(qb + (r0s << 6) + src0, &qs[bf][tid * 8]);
      gl2lds16(qb + (r1s << 6) + src1, &qs[bf][i1 * 8]);
      gl2lds16(kb + (r0s << 6) + src0, &ks[bf][tid * 8]);
      gl2lds16(kb + (r1s << 6) + src1, &ks[bf][i1 * 8]);
    }
    const int bf = h & 1;
    const unsigned short* qt = &qs[bf][(w * 16 + l16) * 64];
    u16x8 a0 = *(const u16x8*)(qt + sw0);
    u16x8 a1 = *(const u16x8*)(qt + sw1);
    f32x4 mv = *(const f32x4*)&ml[h][w * 16 + quad * 4];
    f32x4 rv = *(const f32x4*)&rl[h][w * 16 + quad * 4];
    f32x4 cv = *(const f32x4*)&cl[h][w * 16 + quad * 4];
#pragma unroll
    for (int ni = 0; ni < 4; ni++) {
      const unsigned short* kt = &ks[bf][(ni * 16 + l16) * 64];
      u16x8 b0 = *(const u16x8*)(kt + sw0);
      u16x8 b1 = *(const u16x8*)(kt + sw1);
      f32x4 scv = {0.f, 0.f, 0.f, 0.f};
      scv = mfma16(a0, b0, scv);
      scv = mfma16(a1, b1, scv);
#pragma unroll
      for (int r = 0; r < 4; r++) {
        float e = __expf(scv[r] - mv[r]);
        accA[ni][r] += e * rv[r];
        accS[ni][r] += e * __builtin_amdgcn_rcpf(e + cv[r]);
      }
    }
  }
  const float inv_h = 1.0f / 16.0f;
  const int lrow0 = l0 + w * 16;
#pragma unroll
  for (int ni = 0; ni < 4; ni++) {
#pragma unroll
    for (int r = 0; r < 4; r++) {
      int l = lrow0 + quad * 4 + r;
      int s = s0 + ni * 16 + l16;
      size_t idx = ((size_t)nb * 1024 + l) * 1024 + s;
      attn_out[idx] = accA[ni][r] * inv_h;
      sig_out[idx] = accS[ni][r] * inv_h;
    }
  }
}

// ---------------- K5: output projection (bf16 in, m97-style) ----------------
__global__ __launch_bounds__(256) void out_gemm(
    const unsigned short* __restrict__ o_h, const unsigned short* __restrict__ Wb,
    const float* __restrict__ bias, float* __restrict__ out) {
  __shared__ __align__(16) unsigned short As[2][4096];
  __shared__ __align__(16) unsigned short Bs[2][4096];
  const int tid = threadIdx.x;
  const int bm = blockIdx.x, bn = blockIdx.y;
  const unsigned short* Ag = o_h + (size_t)bm * 128 * 1024;
  const unsigned short* Bg = Wb + (size_t)bn * 128 * 1024;

  const int w = tid >> 6, lane = tid & 63;
  const int wm = w & 1, wn = w >> 1;
  const int quad = lane >> 4, l16 = lane & 15;

  f32x4 acc[4][4];
#pragma unroll
  for (int i = 0; i < 4; i++)
#pragma unroll
    for (int j = 0; j < 4; j++) { f32x4 zz = {0.f, 0.f, 0.f, 0.f}; acc[i][j] = zz; }

  stage_tile(Ag, As[0], tid);
  stage_tile(Bg, Bs[0], tid);

  for (int kk = 0; kk < 32; kk++) {
    __syncthreads();
    if (kk + 1 < 32) {
      const int bf = (kk + 1) & 1;
      stage_tile(Ag + (kk + 1) * 32, As[bf], tid);
      stage_tile(Bg + (kk + 1) * 32, Bs[bf], tid);
    }
    const int cb = kk & 1;
    u16x8 af[4], bfv[4];
#pragma unroll
    for (int mi = 0; mi < 4; mi++) {
      int r = wm * 64 + mi * 16 + l16;
      af[mi] = *(const u16x8*)&As[cb][frag_off(r, quad)];
    }
#pragma unroll
    for (int ni = 0; ni < 4; ni++) {
      int r = wn * 64 + ni * 16 + l16;
      bfv[ni] = *(const u16x8*)&Bs[cb][frag_off(r, quad)];
    }
#pragma unroll
    for (int mi = 0; mi < 4; mi++)
#pragma unroll
      for (int ni = 0; ni < 4; ni++)
        acc[mi][ni] = mfma16(af[mi], bfv[ni], acc[mi][ni]);
  }
#pragma unroll
  for (int ni = 0; ni < 4; ni++) {
    int col = bn * 128 + wn * 64 + ni * 16 + l16;
    float bv = bias[col];
#pragma unroll
    for (int mi = 0; mi < 4; mi++) {
#pragma unroll
      for (int r = 0; r < 4; r++) {
        int t = bm * 128 + wm * 64 + mi * 16 + quad * 4 + r;
        out[(size_t)t * E_DIM + col] = acc[mi][ni][r] + bv;
      }
    }
  }
}

extern "C" void kernel_launch(void* const* d_in, const int* in_sizes, int n_in,
                              void* d_out, int out_size, void* d_ws, size_t ws_size,
                              hipStream_t stream) {
  const float* qin  = (const float*)d_in[0];
  const float* kin  = (const float*)d_in[1];
  const float* vin  = (const float*)d_in[2];
  const float* Wqkv = (const float*)d_in[3];
  const float* bqkv = (const float*)d_in[4];
  const float* Wout = (const float*)d_in[5];
  const float* bout = (const float*)d_in[6];
  float* out      = (float*)d_out;
  float* attn_out = out + 4194304;
  float* sig_out  = out + 8388608;

  // ws layout (u16 units from q_hm):
  unsigned short* q_hm = (unsigned short*)d_ws;      // [64][1024][64] bf16
  unsigned short* k_hm = q_hm + 4194304;             // [64][1024][64]
  unsigned short* v_t  = q_hm + 8388608;             // [64][64][1024]
  unsigned short* o_h  = q_hm + 12582912;            // [4096][1024]
  float* m_ws = (float*)(q_hm + 16777216);           // [64*1024]
  float* r_ws = m_ws + 65536;                        // [64*1024]

  // scratch aliases (dead-region reuse):
  // qb/kb/vb live in d_out's attn/sig region (written later by weights_kernel)
  unsigned short* qb = (unsigned short*)(out + 4194304);  // 8.4M u16
  unsigned short* kb = qb + 4194304;
  unsigned short* vb = qb + 8388608;
  // Wqkvb lives in o_h region (o_h written later by attn_kernel)
  unsigned short* Wqkvb = o_h;                            // 3.15M u16 (< 4.19M)
  // Woutb lives in v_t region (v_t dead after attn_kernel); cast after attn
  unsigned short* Woutb = v_t;                            // 1.05M u16

  cast_kernel<<<dim3(2048, 4), 256, 0, stream>>>(
      qin, kin, vin, Wqkv, qb, kb, vb, Wqkvb,
      4194304, 4194304, 4194304, 3145728);
  qkv_gemm<<<dim3(32, 8, 3), 256, 0, stream>>>(qb, kb, vb, Wqkvb, bqkv,
                                               q_hm, k_hm, v_t);
  attn_kernel<<<dim3(64, 64), 256, 0, stream>>>(q_hm, k_hm, v_t, o_h, m_ws, r_ws);
  cast_kernel<<<dim3(512, 1), 256, 0, stream>>>(
      Wout, Wout, Wout, Wout, Woutb, Woutb, Woutb, Woutb,
      1048576, 0, 0, 0);
  weights_kernel<<<dim3(16, 16, 4), 256, 0, stream>>>(q_hm, k_hm, m_ws, r_ws,
                                                      attn_out, sig_out);
  out_gemm<<<dim3(32, 8), 256, 0, stream>>>(o_h, Woutb, bout, out);
}

// Round 6
// 291.126 us; speedup vs baseline: 1.4098x; 1.0533x over previous
//
#include <hip/hip_runtime.h>

// dims
#define L_DIM 1024
#define E_DIM 1024
#define NB 4
#define H_NUM 16
#define HD_DIM 64
#define T_TOK 4096   // L*NB
#define NHB 64       // NB*H_NUM

typedef float f32x4 __attribute__((ext_vector_type(4)));
typedef unsigned short u16x8 __attribute__((ext_vector_type(8)));
typedef unsigned short u16x4 __attribute__((ext_vector_type(4)));
typedef __bf16 bf16x8 __attribute__((ext_vector_type(8)));

__device__ inline unsigned short f2bf(float f) {
  unsigned int u = __builtin_bit_cast(unsigned int, f);
  u += 0x7FFFu + ((u >> 16) & 1u);
  return (unsigned short)(u >> 16);
}
__device__ inline f32x4 mfma16(u16x8 a, u16x8 b, f32x4 c) {
  return __builtin_amdgcn_mfma_f32_16x16x32_bf16(
      __builtin_bit_cast(bf16x8, a), __builtin_bit_cast(bf16x8, b), c, 0, 0, 0);
}

// async global->LDS 16B copy
__device__ __forceinline__ void gl2lds16(const void* g, void* l) {
  auto gp = reinterpret_cast<const __attribute__((address_space(1))) unsigned int*>(
      reinterpret_cast<unsigned long long>(g));
  auto lp = reinterpret_cast<__attribute__((address_space(3))) unsigned int*>(
      static_cast<unsigned int>(reinterpret_cast<unsigned long long>(l)));
  __builtin_amdgcn_global_load_lds(gp, lp, 16, 0, 0);
}

// ---------------- K0: f32 -> bf16 cast (up to 4 arrays per launch) ----------------
__global__ __launch_bounds__(256) void cast_kernel(
    const float* __restrict__ s0, const float* __restrict__ s1,
    const float* __restrict__ s2, const float* __restrict__ s3,
    unsigned short* __restrict__ d0, unsigned short* __restrict__ d1,
    unsigned short* __restrict__ d2, unsigned short* __restrict__ d3,
    int n0, int n1, int n2, int n3) {
  const int y = blockIdx.y;
  const float* s = (y == 0) ? s0 : (y == 1) ? s1 : (y == 2) ? s2 : s3;
  unsigned short* d = (y == 0) ? d0 : (y == 1) ? d1 : (y == 2) ? d2 : d3;
  const int n = (y == 0) ? n0 : (y == 1) ? n1 : (y == 2) ? n2 : n3;
  int idx = (blockIdx.x * 256 + threadIdx.x) * 8;
  const int stride = gridDim.x * 256 * 8;
  for (; idx < n; idx += stride) {
    float4 a = *(const float4*)(s + idx);
    float4 b = *(const float4*)(s + idx + 4);
    u16x8 o = {f2bf(a.x), f2bf(a.y), f2bf(a.z), f2bf(a.w),
               f2bf(b.x), f2bf(b.y), f2bf(b.z), f2bf(b.w)};
    *(u16x8*)(d + idx) = o;
  }
}

// ---- shared GEMM staging: 128 rows x 32 k bf16 tile (8 KB), swizzled ----
__device__ __forceinline__ void stage_tile(const unsigned short* __restrict__ g,
                                           unsigned short* lbuf, int tid) {
  const int r = tid >> 2, c = tid & 3;
  const int sc = c ^ ((r ^ (r >> 2)) & 3);
  gl2lds16(g + (size_t)r * 1024 + sc * 8, lbuf + tid * 8);
  const int r2 = r + 64;
  gl2lds16(g + (size_t)r2 * 1024 + sc * 8, lbuf + (tid + 256) * 8);
}
__device__ __forceinline__ int frag_off(int r, int q) {
  return r * 32 + ((q ^ ((r ^ (r >> 2)) & 3)) << 3);
}

// ---------------- K1: packed QKV projection (bf16 in, m97-style) ----------------
__global__ __launch_bounds__(256) void qkv_gemm(
    const unsigned short* __restrict__ qb, const unsigned short* __restrict__ kb,
    const unsigned short* __restrict__ vb, const unsigned short* __restrict__ Wb,
    const float* __restrict__ bias, unsigned short* __restrict__ q_hm,
    unsigned short* __restrict__ k_hm, unsigned short* __restrict__ v_t) {
  __shared__ __align__(16) unsigned short As[2][4096];
  __shared__ __align__(16) unsigned short Bs[2][4096];
  const int tid = threadIdx.x;
  const int bm = blockIdx.x, bn = blockIdx.y, z = blockIdx.z;
  const unsigned short* Ag = ((z == 0) ? qb : (z == 1) ? kb : vb) + (size_t)bm * 128 * 1024;
  const unsigned short* Bg = Wb + (size_t)z * 1048576 + (size_t)bn * 128 * 1024;
  const float* bc = bias + z * E_DIM;

  const int w = tid >> 6, lane = tid & 63;
  const int wm = w & 1, wn = w >> 1;
  const int quad = lane >> 4, l16 = lane & 15;

  f32x4 acc[4][4];
#pragma unroll
  for (int i = 0; i < 4; i++)
#pragma unroll
    for (int j = 0; j < 4; j++) { f32x4 zz = {0.f, 0.f, 0.f, 0.f}; acc[i][j] = zz; }

  stage_tile(Ag, As[0], tid);
  stage_tile(Bg, Bs[0], tid);

  for (int kk = 0; kk < 32; kk++) {
    __syncthreads();
    if (kk + 1 < 32) {
      const int bf = (kk + 1) & 1;
      stage_tile(Ag + (kk + 1) * 32, As[bf], tid);
      stage_tile(Bg + (kk + 1) * 32, Bs[bf], tid);
    }
    const int cb = kk & 1;
    u16x8 af[4], bfv[4];
#pragma unroll
    for (int mi = 0; mi < 4; mi++) {
      int r = wm * 64 + mi * 16 + l16;
      af[mi] = *(const u16x8*)&As[cb][frag_off(r, quad)];
    }
#pragma unroll
    for (int ni = 0; ni < 4; ni++) {
      int r = wn * 64 + ni * 16 + l16;
      bfv[ni] = *(const u16x8*)&Bs[cb][frag_off(r, quad)];
    }
#pragma unroll
    for (int mi = 0; mi < 4; mi++)
#pragma unroll
      for (int ni = 0; ni < 4; ni++)
        acc[mi][ni] = mfma16(af[mi], bfv[ni], acc[mi][ni]);
  }
#pragma unroll
  for (int ni = 0; ni < 4; ni++) {
    int col = bn * 128 + wn * 64 + ni * 16 + l16;
    float bv = bc[col];
    int h = col >> 6, d = col & 63;
#pragma unroll
    for (int mi = 0; mi < 4; mi++) {
#pragma unroll
      for (int r = 0; r < 4; r++) {
        int t = bm * 128 + wm * 64 + mi * 16 + quad * 4 + r;
        float v = acc[mi][ni][r] + bv;
        int nb = t & 3, pos = t >> 2;
        if (z == 0) {
          v *= 0.125f;
          q_hm[(size_t)((nb * 16 + h) * 1024 + pos) * 64 + d] = f2bf(v);
        } else if (z == 1) {
          k_hm[(size_t)((nb * 16 + h) * 1024 + pos) * 64 + d] = f2bf(v);
        } else {
          v_t[(size_t)((nb * 16 + h) * 64 + d) * 1024 + pos] = f2bf(v);
        }
      }
    }
  }
}

// ---------------- K3: attention core v3: 32 L-rows/block, per-tile P transpose ----------------
// grid (32 l-blocks, 64 heads), 256 thr (4 waves). Scores A=K,B=Q -> D[s][l];
// P kept in registers; PV phase streams P through a small rotating LDS tile.
__global__ __launch_bounds__(256, 2) void attn_kernel(
    const unsigned short* __restrict__ q_hm, const unsigned short* __restrict__ k_hm,
    const unsigned short* __restrict__ v_t, unsigned short* __restrict__ o_h,
    float* __restrict__ m_ws, float* __restrict__ r_ws) {
  __shared__ __align__(16) unsigned short stage[2][4096];   // 64x64 bf16 K/V tile
  __shared__ __align__(16) unsigned short pt[2][32][68];    // rotating P tile (l x s_local)
  __shared__ float red_m[4][32];
  __shared__ float red_s[4][32];

  const int tid = threadIdx.x;
  const int l0 = blockIdx.x * 32;
  const int b = blockIdx.y;
  const int nb = b >> 4, h = b & 15;
  const int w = tid >> 6, lane = tid & 63;
  const int quad = lane >> 4, l16 = lane & 15;

  const int i1 = tid + 256;
  const int r0s = tid >> 3, c0s = tid & 7;
  const int r1s = i1 >> 3, c1s = i1 & 7;
  const int src0 = (c0s ^ (r0s & 7)) * 8;
  const int src1 = (c1s ^ (r1s & 7)) * 8;

  const unsigned short* kbase = k_hm + ((size_t)b << 16);
  const unsigned short* vbase = v_t + ((size_t)b << 16);

  // Q fragments for the 2 l-groups (B-operand, n = l)
  u16x8 bq[2][2];
#pragma unroll
  for (int g = 0; g < 2; g++) {
    const unsigned short* qp =
        q_hm + ((size_t)(b * 1024 + l0 + g * 16 + l16) << 6) + quad * 8;
    bq[g][0] = *(const u16x8*)qp;
    bq[g][1] = *(const u16x8*)(qp + 32);
  }

  f32x4 acc[16][2];
#pragma unroll
  for (int j = 0; j < 16; j++)
#pragma unroll
    for (int g = 0; g < 2; g++) { f32x4 z = {0.f, 0.f, 0.f, 0.f}; acc[j][g] = z; }

  gl2lds16(kbase + ((size_t)r0s << 6) + src0, &stage[0][tid * 8]);
  gl2lds16(kbase + ((size_t)r1s << 6) + src1, &stage[0][i1 * 8]);

  const int myrow = w * 16 + l16;
  const int sw0 = ((quad ^ (l16 & 7)) * 8);
  const int sw1 = (((quad + 4) ^ (l16 & 7)) * 8);

  // ---- phase 1: scores. lane's acc[j][g][r] <-> s = j*64 + w*16 + quad*4 + r,
  //      l = l0 + g*16 + l16 ----
#pragma unroll
  for (int j = 0; j < 16; j++) {
    __syncthreads();
    if (j < 15) {
      int bf = (j + 1) & 1;
      gl2lds16(kbase + ((size_t)((j + 1) * 64 + r0s) << 6) + src0, &stage[bf][tid * 8]);
      gl2lds16(kbase + ((size_t)((j + 1) * 64 + r1s) << 6) + src1, &stage[bf][i1 * 8]);
    } else {
      // stage V tile 0 into buf 0 (free: last K read of buf0 was iter 14)
      gl2lds16(vbase + ((size_t)r0s << 10) + src0, &stage[0][tid * 8]);
      gl2lds16(vbase + ((size_t)r1s << 10) + src1, &stage[0][i1 * 8]);
    }
    const unsigned short* kt = &stage[j & 1][myrow * 64];
    u16x8 ak0 = *(const u16x8*)(kt + sw0);
    u16x8 ak1 = *(const u16x8*)(kt + sw1);
    acc[j][0] = mfma16(ak0, bq[0][0], acc[j][0]);
    acc[j][0] = mfma16(ak1, bq[0][1], acc[j][0]);
    acc[j][1] = mfma16(ak0, bq[1][0], acc[j][1]);
    acc[j][1] = mfma16(ak1, bq[1][1], acc[j][1]);
  }

  // ---- phase 2: softmax stats in registers; exp in place ----
  float lm0 = -3e38f, lm1 = -3e38f;
#pragma unroll
  for (int j = 0; j < 16; j++)
#pragma unroll
    for (int r = 0; r < 4; r++) {
      lm0 = fmaxf(lm0, acc[j][0][r]);
      lm1 = fmaxf(lm1, acc[j][1][r]);
    }
  lm0 = fmaxf(lm0, __shfl_xor(lm0, 16, 64));
  lm0 = fmaxf(lm0, __shfl_xor(lm0, 32, 64));
  lm1 = fmaxf(lm1, __shfl_xor(lm1, 16, 64));
  lm1 = fmaxf(lm1, __shfl_xor(lm1, 32, 64));
  if (lane < 16) { red_m[w][lane] = lm0; red_m[w][lane + 16] = lm1; }
  __syncthreads();
  float m0 = fmaxf(fmaxf(red_m[0][l16], red_m[1][l16]),
                   fmaxf(red_m[2][l16], red_m[3][l16]));
  float m1 = fmaxf(fmaxf(red_m[0][l16 + 16], red_m[1][l16 + 16]),
                   fmaxf(red_m[2][l16 + 16], red_m[3][l16 + 16]));

  float ls0 = 0.f, ls1 = 0.f;
#pragma unroll
  for (int j = 0; j < 16; j++) {
#pragma unroll
    for (int r = 0; r < 4; r++) {
      float e0 = __expf(acc[j][0][r] - m0);
      float e1 = __expf(acc[j][1][r] - m1);
      acc[j][0][r] = e0;
      acc[j][1][r] = e1;
      ls0 += e0;
      ls1 += e1;
    }
  }
  ls0 += __shfl_xor(ls0, 16, 64);
  ls0 += __shfl_xor(ls0, 32, 64);
  ls1 += __shfl_xor(ls1, 16, 64);
  ls1 += __shfl_xor(ls1, 32, 64);
  if (lane < 16) { red_s[w][lane] = ls0; red_s[w][lane + 16] = ls1; }
  __syncthreads();
  float rv0 = 1.0f / (red_s[0][l16] + red_s[1][l16] + red_s[2][l16] + red_s[3][l16]);
  float rv1 = 1.0f / (red_s[0][l16 + 16] + red_s[1][l16 + 16] +
                      red_s[2][l16 + 16] + red_s[3][l16 + 16]);
  if (tid < 32) {
    float mm = fmaxf(fmaxf(red_m[0][tid], red_m[1][tid]),
                     fmaxf(red_m[2][tid], red_m[3][tid]));
    float ss = red_s[0][tid] + red_s[1][tid] + red_s[2][tid] + red_s[3][tid];
    m_ws[b * 1024 + l0 + tid] = mm;
    r_ws[b * 1024 + l0 + tid] = 1.0f / ss;
  }

  // ---- phase 3: PV with rotating P-tile transpose ----
  // write P tile 0
  {
    u16x4 p0 = {f2bf(acc[0][0][0]), f2bf(acc[0][0][1]), f2bf(acc[0][0][2]), f2bf(acc[0][0][3])};
    u16x4 p1 = {f2bf(acc[0][1][0]), f2bf(acc[0][1][1]), f2bf(acc[0][1][2]), f2bf(acc[0][1][3])};
    *(u16x4*)&pt[0][l16][w * 16 + quad * 4] = p0;
    *(u16x4*)&pt[0][16 + l16][w * 16 + quad * 4] = p1;
  }

  f32x4 oacc0 = {0.f, 0.f, 0.f, 0.f};
  f32x4 oacc1 = {0.f, 0.f, 0.f, 0.f};
#pragma unroll
  for (int j = 0; j < 16; j++) {
    __syncthreads();
    if (j < 15) {
      int bf = (j + 1) & 1;
      gl2lds16(vbase + ((size_t)r0s << 10) + (j + 1) * 64 + src0, &stage[bf][tid * 8]);
      gl2lds16(vbase + ((size_t)r1s << 10) + (j + 1) * 64 + src1, &stage[bf][i1 * 8]);
      u16x4 p0 = {f2bf(acc[j + 1][0][0]), f2bf(acc[j + 1][0][1]),
                  f2bf(acc[j + 1][0][2]), f2bf(acc[j + 1][0][3])};
      u16x4 p1 = {f2bf(acc[j + 1][1][0]), f2bf(acc[j + 1][1][1]),
                  f2bf(acc[j + 1][1][2]), f2bf(acc[j + 1][1][3])};
      *(u16x4*)&pt[bf][l16][w * 16 + quad * 4] = p0;
      *(u16x4*)&pt[bf][16 + l16][w * 16 + quad * 4] = p1;
    }
    const unsigned short* vt = &stage[j & 1][myrow * 64];
    u16x8 bv0 = *(const u16x8*)(vt + sw0);
    u16x8 bv1 = *(const u16x8*)(vt + sw1);
    u16x8 ap00 = *(const u16x8*)&pt[j & 1][l16][quad * 8];
    u16x8 ap01 = *(const u16x8*)&pt[j & 1][l16][32 + quad * 8];
    u16x8 ap10 = *(const u16x8*)&pt[j & 1][16 + l16][quad * 8];
    u16x8 ap11 = *(const u16x8*)&pt[j & 1][16 + l16][32 + quad * 8];
    oacc0 = mfma16(ap00, bv0, oacc0);
    oacc0 = mfma16(ap01, bv1, oacc0);
    oacc1 = mfma16(ap10, bv0, oacc1);
    oacc1 = mfma16(ap11, bv1, oacc1);
  }

#pragma unroll
  for (int r = 0; r < 4; r++) {
    int lr = quad * 4 + r;
    float rr0 = __shfl(rv0, lr, 64);   // rv uniform over quads; lane lr has l16==lr
    float rr1 = __shfl(rv1, lr, 64);
    int t0 = (l0 + lr) * 4 + nb;
    int t1 = (l0 + 16 + lr) * 4 + nb;
    o_h[((size_t)t0 << 10) + h * 64 + w * 16 + l16] = f2bf(oacc0[r] * rr0);
    o_h[((size_t)t1 << 10) + h * 64 + w * 16 + l16] = f2bf(oacc1[r] * rr1);
  }
}

// ---------------- K4: head-averaged attn + sigmoid weights (unchanged) ----------------
__global__ __launch_bounds__(256) void weights_kernel(
    const unsigned short* __restrict__ q_hm, const unsigned short* __restrict__ k_hm,
    const float* __restrict__ m_ws, const float* __restrict__ r_ws,
    float* __restrict__ attn_out, float* __restrict__ sig_out) {
  __shared__ __align__(16) unsigned short qs[2][4096];
  __shared__ __align__(16) unsigned short ks[2][4096];
  __shared__ float ml[16][64];
  __shared__ float rl[16][64];
  __shared__ float cl[16][64];

  const int tid = threadIdx.x;
  const int s0 = blockIdx.x * 64;
  const int l0 = blockIdx.y * 64;
  const int nb = blockIdx.z;
  const int w = tid >> 6, lane = tid & 63;
  const int quad = lane >> 4, l16 = lane & 15;

  const int i1 = tid + 256;
  const int r0s = tid >> 3, c0s = tid & 7;
  const int r1s = i1 >> 3, c1s = i1 & 7;
  const int src0 = (c0s ^ (r0s & 7)) * 8;
  const int src1 = (c1s ^ (r1s & 7)) * 8;

  {
    int idx = tid * 4;
    int hh = idx >> 6, ii = idx & 63;
    int bb = nb * 16 + hh;
    float4 mv4 = *(const float4*)&m_ws[bb * 1024 + l0 + ii];
    float4 rv4 = *(const float4*)&r_ws[bb * 1024 + l0 + ii];
    *(float4*)&ml[hh][ii] = mv4;
    *(float4*)&rl[hh][ii] = rv4;
    float4 cv4 = {__expf(-mv4.x), __expf(-mv4.y), __expf(-mv4.z), __expf(-mv4.w)};
    *(float4*)&cl[hh][ii] = cv4;
  }

  {
    int bb = nb * 16;
    const unsigned short* qb = q_hm + ((size_t)(bb * 1024 + l0) << 6);
    const unsigned short* kb = k_hm + ((size_t)(bb * 1024 + s0) << 6);
    gl2lds16(qb + (r0s << 6) + src0, &qs[0][tid * 8]);
    gl2lds16(qb + (r1s << 6) + src1, &qs[0][i1 * 8]);
    gl2lds16(kb + (r0s << 6) + src0, &ks[0][tid * 8]);
    gl2lds16(kb + (r1s << 6) + src1, &ks[0][i1 * 8]);
  }

  const int sw0 = ((quad ^ (l16 & 7)) * 8);
  const int sw1 = (((quad + 4) ^ (l16 & 7)) * 8);

  f32x4 accA[4], accS[4];
#pragma unroll
  for (int i = 0; i < 4; i++) {
    f32x4 zz = {0.f, 0.f, 0.f, 0.f};
    accA[i] = zz; accS[i] = zz;
  }

#pragma unroll
  for (int h = 0; h < 16; h++) {
    __syncthreads();
    if (h + 1 < 16) {
      int bf = (h + 1) & 1;
      int bb = nb * 16 + h + 1;
      const unsigned short* qb = q_hm + ((size_t)(bb * 1024 + l0) << 6);
      const unsigned short* kb = k_hm + ((size_t)(bb * 1024 + s0) << 6);
      gl2lds16(qb + (r0s << 6) + src0, &qs[bf][tid * 8]);
      gl2lds16(qb + (r1s << 6) + src1, &qs[bf][i1 * 8]);
      gl2lds16(kb + (r0s << 6) + src0, &ks[bf][tid * 8]);
      gl2lds16(kb + (r1s << 6) + src1, &ks[bf][i1 * 8]);
    }
    const int bf = h & 1;
    const unsigned short* qt = &qs[bf][(w * 16 + l16) * 64];
    u16x8 a0 = *(const u16x8*)(qt + sw0);
    u16x8 a1 = *(const u16x8*)(qt + sw1);
    f32x4 mv = *(const f32x4*)&ml[h][w * 16 + quad * 4];
    f32x4 rv = *(const f32x4*)&rl[h][w * 16 + quad * 4];
    f32x4 cv = *(const f32x4*)&cl[h][w * 16 + quad * 4];
#pragma unroll
    for (int ni = 0; ni < 4; ni++) {
      const unsigned short* kt = &ks[bf][(ni * 16 + l16) * 64];
      u16x8 b0 = *(const u16x8*)(kt + sw0);
      u16x8 b1 = *(const u16x8*)(kt + sw1);
      f32x4 scv = {0.f, 0.f, 0.f, 0.f};
      scv = mfma16(a0, b0, scv);
      scv = mfma16(a1, b1, scv);
#pragma unroll
      for (int r = 0; r < 4; r++) {
        float e = __expf(scv[r] - mv[r]);
        accA[ni][r] += e * rv[r];
        accS[ni][r] += e * __builtin_amdgcn_rcpf(e + cv[r]);
      }
    }
  }
  const float inv_h = 1.0f / 16.0f;
  const int lrow0 = l0 + w * 16;
#pragma unroll
  for (int ni = 0; ni < 4; ni++) {
#pragma unroll
    for (int r = 0; r < 4; r++) {
      int l = lrow0 + quad * 4 + r;
      int s = s0 + ni * 16 + l16;
      size_t idx = ((size_t)nb * 1024 + l) * 1024 + s;
      attn_out[idx] = accA[ni][r] * inv_h;
      sig_out[idx] = accS[ni][r] * inv_h;
    }
  }
}

// ---------------- K5: output projection (bf16 in, m97-style) ----------------
__global__ __launch_bounds__(256) void out_gemm(
    const unsigned short* __restrict__ o_h, const unsigned short* __restrict__ Wb,
    const float* __restrict__ bias, float* __restrict__ out) {
  __shared__ __align__(16) unsigned short As[2][4096];
  __shared__ __align__(16) unsigned short Bs[2][4096];
  const int tid = threadIdx.x;
  const int bm = blockIdx.x, bn = blockIdx.y;
  const unsigned short* Ag = o_h + (size_t)bm * 128 * 1024;
  const unsigned short* Bg = Wb + (size_t)bn * 128 * 1024;

  const int w = tid >> 6, lane = tid & 63;
  const int wm = w & 1, wn = w >> 1;
  const int quad = lane >> 4, l16 = lane & 15;

  f32x4 acc[4][4];
#pragma unroll
  for (int i = 0; i < 4; i++)
#pragma unroll
    for (int j = 0; j < 4; j++) { f32x4 zz = {0.f, 0.f, 0.f, 0.f}; acc[i][j] = zz; }

  stage_tile(Ag, As[0], tid);
  stage_tile(Bg, Bs[0], tid);

  for (int kk = 0; kk < 32; kk++) {
    __syncthreads();
    if (kk + 1 < 32) {
      const int bf = (kk + 1) & 1;
      stage_tile(Ag + (kk + 1) * 32, As[bf], tid);
      stage_tile(Bg + (kk + 1) * 32, Bs[bf], tid);
    }
    const int cb = kk & 1;
    u16x8 af[4], bfv[4];
#pragma unroll
    for (int mi = 0; mi < 4; mi++) {
      int r = wm * 64 + mi * 16 + l16;
      af[mi] = *(const u16x8*)&As[cb][frag_off(r, quad)];
    }
#pragma unroll
    for (int ni = 0; ni < 4; ni++) {
      int r = wn * 64 + ni * 16 + l16;
      bfv[ni] = *(const u16x8*)&Bs[cb][frag_off(r, quad)];
    }
#pragma unroll
    for (int mi = 0; mi < 4; mi++)
#pragma unroll
      for (int ni = 0; ni < 4; ni++)
        acc[mi][ni] = mfma16(af[mi], bfv[ni], acc[mi][ni]);
  }
#pragma unroll
  for (int ni = 0; ni < 4; ni++) {
    int col = bn * 128 + wn * 64 + ni * 16 + l16;
    float bv = bias[col];
#pragma unroll
    for (int mi = 0; mi < 4; mi++) {
#pragma unroll
      for (int r = 0; r < 4; r++) {
        int t = bm * 128 + wm * 64 + mi * 16 + quad * 4 + r;
        out[(size_t)t * E_DIM + col] = acc[mi][ni][r] + bv;
      }
    }
  }
}

extern "C" void kernel_launch(void* const* d_in, const int* in_sizes, int n_in,
                              void* d_out, int out_size, void* d_ws, size_t ws_size,
                              hipStream_t stream) {
  const float* qin  = (const float*)d_in[0];
  const float* kin  = (const float*)d_in[1];
  const float* vin  = (const float*)d_in[2];
  const float* Wqkv = (const float*)d_in[3];
  const float* bqkv = (const float*)d_in[4];
  const float* Wout = (const float*)d_in[5];
  const float* bout = (const float*)d_in[6];
  float* out      = (float*)d_out;
  float* attn_out = out + 4194304;
  float* sig_out  = out + 8388608;

  unsigned short* q_hm = (unsigned short*)d_ws;      // [64][1024][64] bf16
  unsigned short* k_hm = q_hm + 4194304;             // [64][1024][64]
  unsigned short* v_t  = q_hm + 8388608;             // [64][64][1024]
  unsigned short* o_h  = q_hm + 12582912;            // [4096][1024]
  float* m_ws = (float*)(q_hm + 16777216);           // [64*1024]
  float* r_ws = m_ws + 65536;                        // [64*1024]

  unsigned short* qb = (unsigned short*)(out + 4194304);  // alias: attn/sig region
  unsigned short* kb = qb + 4194304;
  unsigned short* vb = qb + 8388608;
  unsigned short* Wqkvb = o_h;                            // alias: o_h region
  unsigned short* Woutb = v_t;                            // alias: v_t region (cast after attn)

  cast_kernel<<<dim3(2048, 4), 256, 0, stream>>>(
      qin, kin, vin, Wqkv, qb, kb, vb, Wqkvb,
      4194304, 4194304, 4194304, 3145728);
  qkv_gemm<<<dim3(32, 8, 3), 256, 0, stream>>>(qb, kb, vb, Wqkvb, bqkv,
                                               q_hm, k_hm, v_t);
  attn_kernel<<<dim3(32, 64), 256, 0, stream>>>(q_hm, k_hm, v_t, o_h, m_ws, r_ws);
  cast_kernel<<<dim3(512, 1), 256, 0, stream>>>(
      Wout, Wout, Wout, Wout, Woutb, Woutb, Woutb, Woutb,
      1048576, 0, 0, 0);
  weights_kernel<<<dim3(16, 16, 4), 256, 0, stream>>>(q_hm, k_hm, m_ws, r_ws,
                                                      attn_out, sig_out);
  out_gemm<<<dim3(32, 8), 256, 0, stream>>>(o_h, Woutb, bout, out);
}